// Round 4
// baseline (398.454 us; speedup 1.0000x reference)
//
#include <hip/hip_runtime.h>
#include <hip/hip_bf16.h>
#include <float.h>

// B=4, S=2048, D=1024 causal attention with input projections.
// out = softmax(mask((q@Wq)(k@Wk)^T / 32)) @ (v@Wv)
//
// Numerics: logits std ~342 -> q1/k1 and QK^T use bf16x2 (hi/lo) split
// arithmetic (3 MFMAs), ~2^-18 effective precision. Splits MUST be
// round-to-nearest (truncation split = 4x error, failed R2).
// v path is plain bf16 (convex combination).
//
// R4 scheduling: proj_q+proj_k merged (1024 blocks -> 4-5/CU implicit TLP);
// qk2/pv2/proj_v get explicit 2-phase prefetch dbuf (grid-starved at 2/CU).

typedef __attribute__((ext_vector_type(8))) short bf16x8;
typedef __attribute__((ext_vector_type(4))) float f32x4;

#define MFMA16 __builtin_amdgcn_mfma_f32_16x16x32_bf16

#if __has_builtin(__builtin_amdgcn_perm)
#define PERM2BF(hi32, lo32) __builtin_amdgcn_perm((hi32), (lo32), 0x07060302u)
#else
#define PERM2BF(hi32, lo32) (((lo32) >> 16) | ((hi32) & 0xffff0000u))
#endif

union U8 { bf16x8 v; unsigned w[4]; };

__device__ __forceinline__ ushort f2bf(float x) {
  union { float f; unsigned u; } v; v.f = x;
  unsigned r = v.u + 0x7fffu + ((v.u >> 16) & 1u);
  return (ushort)(r >> 16);
}
__device__ __forceinline__ float bf2f(ushort h) {
  union { unsigned u; float f; } v; v.u = ((unsigned)h) << 16;
  return v.f;
}
__device__ __forceinline__ void splitf(float x, ushort& hi, ushort& lo) {
  hi = f2bf(x);
  lo = f2bf(x - bf2f(hi));
}
// round-to-nearest-even bf16 as a 32-bit float pattern (low 16 zeroed)
__device__ __forceinline__ unsigned rnbits(unsigned u) {
  return (u + 0x7fffu + ((u >> 16) & 1u)) & 0xffff0000u;
}

// In-register ROUND-TO-NEAREST split of 8 consecutive LDS floats into hi/lo
// bf16x8 fragments.
__device__ __forceinline__ void split8(const float* lp, bf16x8& hi, bf16x8& lo) {
  U8 H, L;
#pragma unroll
  for (int p = 0; p < 4; ++p) {
    const float x0 = lp[2 * p], x1 = lp[2 * p + 1];
    const unsigned r0 = rnbits(__float_as_uint(x0));
    const unsigned r1 = rnbits(__float_as_uint(x1));
    const float d0 = x0 - __uint_as_float(r0);
    const float d1 = x1 - __uint_as_float(r1);
    const unsigned s0 = rnbits(__float_as_uint(d0));
    const unsigned s1 = rnbits(__float_as_uint(d1));
    H.w[p] = PERM2BF(r1, r0);
    L.w[p] = PERM2BF(s1, s0);
  }
  hi = H.v; lo = L.v;
}

// Plain fp32 -> bf16x8 (round-to-nearest) from 8 consecutive LDS floats.
__device__ __forceinline__ bf16x8 cvt8(const float* lp) {
  U8 H;
#pragma unroll
  for (int p = 0; p < 4; ++p) {
    const unsigned u0 = rnbits(__float_as_uint(lp[2 * p]));
    const unsigned u1 = rnbits(__float_as_uint(lp[2 * p + 1]));
    H.w[p] = PERM2BF(u1, u0);
  }
  return H.v;
}

// ---------------------------------------------------------------------------
// global_load_lds staging helpers. LDS layout linear [128][BK] (no pad).
// ---------------------------------------------------------------------------
#define GLOAD16(gp, lp)                                                        \
  __builtin_amdgcn_global_load_lds(                                            \
      (const __attribute__((address_space(1))) void*)(gp),                     \
      (__attribute__((address_space(3))) void*)(lp), 16, 0, 0)

// bf16 slab 128 x 32 (8 KB, 8 chunks; 16 rows/chunk, 4 lanes/row)
__device__ __forceinline__ void stage_bf16_32(const ushort* g, int pitch,
                                              ushort* lds, int w, int lane) {
#pragma unroll
  for (int i = 0; i < 2; ++i) {
    const int c = w * 2 + i;
    const int row = c * 16 + (lane >> 2);
    const int kp = (lane & 3) * 8;
    GLOAD16(g + (size_t)row * pitch + kp, lds + c * 512);
  }
}
// bf16 slab 128 x 64 (16 KB, 16 chunks; 8 rows/chunk, 8 lanes/row)
__device__ __forceinline__ void stage_bf16_64(const ushort* g, int pitch,
                                              ushort* lds, int w, int lane) {
#pragma unroll
  for (int i = 0; i < 4; ++i) {
    const int c = w * 4 + i;
    const int row = c * 8 + (lane >> 3);
    const int kp = (lane & 7) * 8;
    GLOAD16(g + (size_t)row * pitch + kp, lds + c * 512);
  }
}
// fp32 slab 128 x 32 (16 KB, 16 chunks; 8 rows/chunk, 8 lanes/row)
__device__ __forceinline__ void stage_f32_32(const float* g, int pitch,
                                             float* lds, int w, int lane) {
#pragma unroll
  for (int i = 0; i < 4; ++i) {
    const int c = w * 4 + i;
    const int row = c * 8 + (lane >> 3);
    const int kp = (lane & 7) * 4;
    GLOAD16(g + (size_t)row * pitch + kp, lds + c * 256);
  }
}

// ---------------------------------------------------------------------------
// W transpose + convert: Wt[n][k] = W[k][n] as bf16 hi/lo (or hi only).
// ---------------------------------------------------------------------------
template <bool SPLIT>
__global__ __launch_bounds__(256) void wt_conv(const float* __restrict__ W,
                                               ushort* __restrict__ Th,
                                               ushort* __restrict__ Tl) {
  __shared__ float t[32][33];
  const int bx = blockIdx.x, by = blockIdx.y;  // k-tile, n-tile
  const int r = threadIdx.x >> 3, c4 = (threadIdx.x & 7) * 4;
  const float4 x =
      *reinterpret_cast<const float4*>(&W[(size_t)(bx * 32 + r) * 1024 + by * 32 + c4]);
  t[r][c4] = x.x; t[r][c4 + 1] = x.y; t[r][c4 + 2] = x.z; t[r][c4 + 3] = x.w;
  __syncthreads();
  ushort h[4], l[4];
#pragma unroll
  for (int j = 0; j < 4; ++j) splitf(t[c4 + j][r], h[j], l[j]);
  const size_t o = (size_t)(by * 32 + r) * 1024 + bx * 32 + c4;
  *reinterpret_cast<ushort4*>(&Th[o]) = ushort4{h[0], h[1], h[2], h[3]};
  if (SPLIT)
    *reinterpret_cast<ushort4*>(&Tl[o]) = ushort4{l[0], l[1], l[2], l[3]};
}

// ---------------------------------------------------------------------------
// q/k projection, MERGED: blockIdx.z selects (q,Wq)->q1 or (k,Wk)->k1.
// 1024 blocks -> 4-5 resident/CU (implicit TLP hides barrier drain).
// A staged raw fp32, split in-register; B pre-split bf16 hi/lo; 3 MFMA.
// ---------------------------------------------------------------------------
__global__ __launch_bounds__(256) void proj_qk(
    const float* __restrict__ A0, const float* __restrict__ A1,
    const ushort* __restrict__ Bth0, const ushort* __restrict__ Btl0,
    const ushort* __restrict__ Bth1, const ushort* __restrict__ Btl1,
    ushort* __restrict__ Ohi0, ushort* __restrict__ Olo0,
    ushort* __restrict__ Ohi1, ushort* __restrict__ Olo1) {
  __shared__ float As[128 * 32];
  __shared__ ushort Bhs[128 * 32], Bls[128 * 32];
  const int z = blockIdx.z;
  const float* A = z ? A1 : A0;
  const ushort* Bth = z ? Bth1 : Bth0;
  const ushort* Btl = z ? Btl1 : Btl0;
  ushort* Ohi = z ? Ohi1 : Ohi0;
  ushort* Olo = z ? Olo1 : Olo0;
  const int tid = threadIdx.x, lane = tid & 63, w = tid >> 6;
  const int wr = w >> 1, wc = w & 1;
  const int lr = lane & 15, kg = lane >> 4;
  const int m0 = blockIdx.y * 128, n0 = blockIdx.x * 128;
  f32x4 acc[4][4] = {};

  for (int k0 = 0; k0 < 1024; k0 += 32) {
    stage_f32_32(A + (size_t)m0 * 1024 + k0, 1024, As, w, lane);
    stage_bf16_32(Bth + (size_t)n0 * 1024 + k0, 1024, Bhs, w, lane);
    stage_bf16_32(Btl + (size_t)n0 * 1024 + k0, 1024, Bls, w, lane);
    __syncthreads();
    bf16x8 ah[4], al[4], bh[4], bl[4];
#pragma unroll
    for (int m = 0; m < 4; ++m)
      split8(&As[(wr * 64 + m * 16 + lr) * 32 + kg * 8], ah[m], al[m]);
#pragma unroll
    for (int n = 0; n < 4; ++n) {
      bh[n] = *reinterpret_cast<bf16x8*>(&Bhs[(wc * 64 + n * 16 + lr) * 32 + kg * 8]);
      bl[n] = *reinterpret_cast<bf16x8*>(&Bls[(wc * 64 + n * 16 + lr) * 32 + kg * 8]);
    }
#pragma unroll
    for (int m = 0; m < 4; ++m)
#pragma unroll
      for (int n = 0; n < 4; ++n) {
        acc[m][n] = MFMA16(ah[m], bh[n], acc[m][n], 0, 0, 0);
        acc[m][n] = MFMA16(ah[m], bl[n], acc[m][n], 0, 0, 0);
        acc[m][n] = MFMA16(al[m], bh[n], acc[m][n], 0, 0, 0);
      }
    __syncthreads();
  }
#pragma unroll
  for (int m = 0; m < 4; ++m)
#pragma unroll
    for (int n = 0; n < 4; ++n)
#pragma unroll
      for (int reg = 0; reg < 4; ++reg) {
        const int gm = m0 + wr * 64 + m * 16 + kg * 4 + reg;
        const int gn = n0 + wc * 64 + n * 16 + lr;
        ushort h, l;
        splitf(acc[m][n][reg], h, l);
        Ohi[(size_t)gm * 1024 + gn] = h;
        Olo[(size_t)gm * 1024 + gn] = l;
      }
}

// ---------------------------------------------------------------------------
// v projection, transposed output: v1t[b][d][j] = sum_k Wv[k][d] v[b,j,k].
// 2-phase prefetch dbuf (512 blocks = 2/CU, needs self-hiding).
// ---------------------------------------------------------------------------
__global__ __launch_bounds__(256) void proj_v(const ushort* __restrict__ Wvt,
                                              const float* __restrict__ V,
                                              ushort* __restrict__ v1t) {
  __shared__ ushort Ahs[2][128 * 32];
  __shared__ float Bs[2][128 * 32];
  const int tid = threadIdx.x, lane = tid & 63, w = tid >> 6;
  const int wr = w >> 1, wc = w & 1;
  const int lr = lane & 15, kg = lane >> 4;
  const int m0 = blockIdx.y * 128;   // d-tile
  const int n0 = blockIdx.x * 128;   // global j tile (8192 rows)
  const ushort* abase = Wvt + (size_t)m0 * 1024;
  const float* bbase = V + (size_t)n0 * 1024;
  f32x4 acc[4][4] = {};

  stage_bf16_32(abase, 1024, Ahs[0], w, lane);
  stage_f32_32(bbase, 1024, Bs[0], w, lane);
  __syncthreads();
  int cur = 0;
  for (int t = 0; t < 32; ++t) {
    if (t < 31) {
      const int kn = (t + 1) * 32;
      stage_bf16_32(abase + kn, 1024, Ahs[cur ^ 1], w, lane);
      stage_f32_32(bbase + kn, 1024, Bs[cur ^ 1], w, lane);
    }
    bf16x8 ah[4], bh[4];
#pragma unroll
    for (int m = 0; m < 4; ++m)
      ah[m] = *reinterpret_cast<bf16x8*>(&Ahs[cur][(wr * 64 + m * 16 + lr) * 32 + kg * 8]);
#pragma unroll
    for (int n = 0; n < 4; ++n)
      bh[n] = cvt8(&Bs[cur][(wc * 64 + n * 16 + lr) * 32 + kg * 8]);
#pragma unroll
    for (int m = 0; m < 4; ++m)
#pragma unroll
      for (int n = 0; n < 4; ++n)
        acc[m][n] = MFMA16(ah[m], bh[n], acc[m][n], 0, 0, 0);
    __syncthreads();
    cur ^= 1;
  }
#pragma unroll
  for (int m = 0; m < 4; ++m)
#pragma unroll
    for (int n = 0; n < 4; ++n)
#pragma unroll
      for (int reg = 0; reg < 4; ++reg) {
        const int gm = m0 + wr * 64 + m * 16 + kg * 4 + reg;  // d
        const int gn = n0 + wc * 64 + n * 16 + lr;            // global j
        const int b = gn >> 11, jj = gn & 2047;
        v1t[((size_t)b << 21) + (size_t)gm * 2048 + jj] = f2bf(acc[m][n][reg]);
      }
}

// ---------------------------------------------------------------------------
// QK^T, bf16x2 split (3 MFMA), causal triangular grid, 2-phase prefetch dbuf
// (544 blocks = 2.1/CU; 64 KB LDS caps residency at 2 — matched).
// ---------------------------------------------------------------------------
__global__ __launch_bounds__(256) void qk2(
    const ushort* __restrict__ q1h, const ushort* __restrict__ q1l,
    const ushort* __restrict__ k1h, const ushort* __restrict__ k1l,
    float* __restrict__ scores) {
  __shared__ ushort Ahs[2][128 * 32], Als[2][128 * 32];
  __shared__ ushort Bhs[2][128 * 32], Bls[2][128 * 32];
  const int tid = threadIdx.x, lane = tid & 63, w = tid >> 6;
  const int wr = w >> 1, wc = w & 1;
  const int lr = lane & 15, kg = lane >> 4;
  const int b = blockIdx.y;
  int p = blockIdx.x, ti = 0, accp = 0;
  while (accp + ti + 1 <= p) { accp += ti + 1; ++ti; }
  const int tj = p - accp;
  const ushort* qh = q1h + ((size_t)b * 2048 + ti * 128) * 1024;
  const ushort* ql = q1l + ((size_t)b * 2048 + ti * 128) * 1024;
  const ushort* kh = k1h + ((size_t)b * 2048 + tj * 128) * 1024;
  const ushort* kl = k1l + ((size_t)b * 2048 + tj * 128) * 1024;
  f32x4 acc[4][4] = {};

  stage_bf16_32(qh, 1024, Ahs[0], w, lane);
  stage_bf16_32(ql, 1024, Als[0], w, lane);
  stage_bf16_32(kh, 1024, Bhs[0], w, lane);
  stage_bf16_32(kl, 1024, Bls[0], w, lane);
  __syncthreads();
  int cur = 0;
  for (int t = 0; t < 32; ++t) {
    if (t < 31) {
      const int kn = (t + 1) * 32;
      stage_bf16_32(qh + kn, 1024, Ahs[cur ^ 1], w, lane);
      stage_bf16_32(ql + kn, 1024, Als[cur ^ 1], w, lane);
      stage_bf16_32(kh + kn, 1024, Bhs[cur ^ 1], w, lane);
      stage_bf16_32(kl + kn, 1024, Bls[cur ^ 1], w, lane);
    }
    bf16x8 ah[4], al[4], bh[4], bl[4];
#pragma unroll
    for (int m = 0; m < 4; ++m) {
      ah[m] = *reinterpret_cast<bf16x8*>(&Ahs[cur][(wr * 64 + m * 16 + lr) * 32 + kg * 8]);
      al[m] = *reinterpret_cast<bf16x8*>(&Als[cur][(wr * 64 + m * 16 + lr) * 32 + kg * 8]);
    }
#pragma unroll
    for (int n = 0; n < 4; ++n) {
      bh[n] = *reinterpret_cast<bf16x8*>(&Bhs[cur][(wc * 64 + n * 16 + lr) * 32 + kg * 8]);
      bl[n] = *reinterpret_cast<bf16x8*>(&Bls[cur][(wc * 64 + n * 16 + lr) * 32 + kg * 8]);
    }
#pragma unroll
    for (int m = 0; m < 4; ++m)
#pragma unroll
      for (int n = 0; n < 4; ++n) {
        acc[m][n] = MFMA16(ah[m], bh[n], acc[m][n], 0, 0, 0);
        acc[m][n] = MFMA16(ah[m], bl[n], acc[m][n], 0, 0, 0);
        acc[m][n] = MFMA16(al[m], bh[n], acc[m][n], 0, 0, 0);
      }
    __syncthreads();
    cur ^= 1;
  }
  const float sc = 0.03125f;  // 1/sqrt(1024)
#pragma unroll
  for (int m = 0; m < 4; ++m)
#pragma unroll
    for (int n = 0; n < 4; ++n)
#pragma unroll
      for (int reg = 0; reg < 4; ++reg) {
        const int gi = ti * 128 + wr * 64 + m * 16 + kg * 4 + reg;
        const int gj = tj * 128 + wc * 64 + n * 16 + lr;
        float v = acc[m][n][reg] * sc;
        if (gj > gi) v = -FLT_MAX;
        scores[((size_t)b * 2048 + gi) * 2048 + gj] = v;
      }
}

// ---------------------------------------------------------------------------
// Row softmax, P written bf16 in place (zeros beyond the causal boundary).
// ---------------------------------------------------------------------------
__global__ __launch_bounds__(256) void softmax_kernel(float* __restrict__ scores) {
  __shared__ float red[8];
  const int rb = blockIdx.x;
  const int b = rb >> 11, r = rb & 2047;
  float* srow = scores + ((size_t)(b * 2048 + r)) * 2048;
  ushort* prow = reinterpret_cast<ushort*>(srow);
  const int valid = r + 1;
  const int tid = threadIdx.x, lane = tid & 63, w = tid >> 6;

  float vals[8];
  float mx = -FLT_MAX;
#pragma unroll
  for (int c = 0; c < 8; ++c) {
    const int j = tid + c * 256;
    vals[c] = (j < valid) ? srow[j] : -FLT_MAX;
    mx = fmaxf(mx, vals[c]);
  }
#pragma unroll
  for (int o = 32; o; o >>= 1) mx = fmaxf(mx, __shfl_xor(mx, o));
  if (lane == 0) red[w] = mx;
  __syncthreads();
  mx = fmaxf(fmaxf(red[0], red[1]), fmaxf(red[2], red[3]));

  float ex[8];
  float sum = 0.f;
#pragma unroll
  for (int c = 0; c < 8; ++c) {
    const int j = tid + c * 256;
    ex[c] = (j < valid) ? __expf(vals[c] - mx) : 0.f;
    sum += ex[c];
  }
#pragma unroll
  for (int o = 32; o; o >>= 1) sum += __shfl_xor(sum, o);
  if (lane == 0) red[4 + w] = sum;
  __syncthreads();
  sum = red[4] + red[5] + red[6] + red[7];
  const float inv = 1.f / sum;
#pragma unroll
  for (int c = 0; c < 8; ++c) {
    const int j = tid + c * 256;
    prow[j] = f2bf(ex[c] * inv);
  }
}

// ---------------------------------------------------------------------------
// PV: out[b,i,:] = P[b,i,:] @ v1. A = P bf16 (pitch 4096), B = v1t (pitch
// 2048), BK=64, 2-phase prefetch dbuf. Causal: K ends at (ti+1)*128.
// ---------------------------------------------------------------------------
__global__ __launch_bounds__(256) void pv2(const float* __restrict__ scores,
                                           const ushort* __restrict__ v1t,
                                           float* __restrict__ out) {
  __shared__ ushort Ps[2][128 * 64], Vs[2][128 * 64];
  const int tid = threadIdx.x, lane = tid & 63, w = tid >> 6;
  const int wr = w >> 1, wc = w & 1;
  const int lr = lane & 15, kg = lane >> 4;
  const int b = blockIdx.z;
  const int ti = 15 - blockIdx.y;  // long blocks first
  const int n0 = blockIdx.x * 128;
  const ushort* pbase =
      reinterpret_cast<const ushort*>(scores + (size_t)b * 2048 * 2048) +
      (size_t)(ti * 128) * 4096;
  const ushort* vbase = v1t + ((size_t)b << 21) + (size_t)n0 * 2048;
  const int nt = 2 * (ti + 1);  // K-steps of 64
  f32x4 acc[4][4] = {};

  stage_bf16_64(pbase, 4096, Ps[0], w, lane);
  stage_bf16_64(vbase, 2048, Vs[0], w, lane);
  __syncthreads();
  int cur = 0;
  for (int t = 0; t < nt; ++t) {
    if (t + 1 < nt) {
      const int kn = (t + 1) * 64;
      stage_bf16_64(pbase + kn, 4096, Ps[cur ^ 1], w, lane);
      stage_bf16_64(vbase + kn, 2048, Vs[cur ^ 1], w, lane);
    }
#pragma unroll
    for (int t2 = 0; t2 < 2; ++t2) {
      bf16x8 pa[4], vb[4];
#pragma unroll
      for (int m = 0; m < 4; ++m)
        pa[m] = *reinterpret_cast<bf16x8*>(
            &Ps[cur][(wr * 64 + m * 16 + lr) * 64 + t2 * 32 + kg * 8]);
#pragma unroll
      for (int n = 0; n < 4; ++n)
        vb[n] = *reinterpret_cast<bf16x8*>(
            &Vs[cur][(wc * 64 + n * 16 + lr) * 64 + t2 * 32 + kg * 8]);
#pragma unroll
      for (int m = 0; m < 4; ++m)
#pragma unroll
        for (int n = 0; n < 4; ++n)
          acc[m][n] = MFMA16(pa[m], vb[n], acc[m][n], 0, 0, 0);
    }
    __syncthreads();
    cur ^= 1;
  }
#pragma unroll
  for (int m = 0; m < 4; ++m)
#pragma unroll
    for (int n = 0; n < 4; ++n)
#pragma unroll
      for (int reg = 0; reg < 4; ++reg) {
        const int gm = ti * 128 + wr * 64 + m * 16 + kg * 4 + reg;
        const int gn = n0 + wc * 64 + n * 16 + lr;
        out[((size_t)b * 2048 + gm) * 1024 + gn] = acc[m][n][reg];
      }
}

extern "C" void kernel_launch(void* const* d_in, const int* in_sizes, int n_in,
                              void* d_out, int out_size, void* d_ws,
                              size_t ws_size, hipStream_t stream) {
  const float* q = (const float*)d_in[0];
  const float* k = (const float*)d_in[1];
  const float* v = (const float*)d_in[2];
  // d_in[3] = causal mask — statically known, ignored.
  const float* Wq = (const float*)d_in[4];
  const float* Wk = (const float*)d_in[5];
  const float* Wv = (const float*)d_in[6];
  float* out = (float*)d_out;

  // Workspace layout with liveness aliasing:
  //   [0, 64M)      scores (fp32, 4x2048x2048) — born at qk2.
  //                 The Wt buffers (10 MB) alias its head; dead before qk2.
  //   [64M, 128M)   q1hi q1lo k1hi k1lo (bf16, 4 x 16 MB)
  //   [128M, 144M)  v1t (bf16, 16 MB)
  char* ws = (char*)d_ws;
  float* scores = (float*)ws;
  ushort* Wqth = (ushort*)ws;
  ushort* Wqtl = Wqth + 1048576;
  ushort* Wkth = Wqth + 2 * 1048576;
  ushort* Wktl = Wqth + 3 * 1048576;
  ushort* Wvt  = Wqth + 4 * 1048576;
  ushort* q1hi = (ushort*)(ws + 67108864);
  ushort* q1lo = q1hi + 8388608;
  ushort* k1hi = q1hi + 2 * 8388608;
  ushort* k1lo = q1hi + 3 * 8388608;
  ushort* v1t  = q1hi + 4 * 8388608;
  const size_t need = 67108864 + 5 * 16777216;  // 150,994,944
  if (ws_size < need) return;

  dim3 blk(256);
  wt_conv<true><<<dim3(32, 32), blk, 0, stream>>>(Wq, Wqth, Wqtl);
  wt_conv<true><<<dim3(32, 32), blk, 0, stream>>>(Wk, Wkth, Wktl);
  wt_conv<false><<<dim3(32, 32), blk, 0, stream>>>(Wv, Wvt, nullptr);
  proj_qk<<<dim3(8, 64, 2), blk, 0, stream>>>(q, k, Wqth, Wqtl, Wkth, Wktl,
                                              q1hi, q1lo, k1hi, k1lo);
  proj_v<<<dim3(64, 8), blk, 0, stream>>>(Wvt, v, v1t);
  qk2<<<dim3(136, 4), blk, 0, stream>>>(q1hi, q1lo, k1hi, k1lo, scores);
  softmax_kernel<<<dim3(8192), blk, 0, stream>>>(scores);
  pv2<<<dim3(8, 16, 4), blk, 0, stream>>>(scores, v1t, out);
}

// Round 5
// 359.841 us; speedup vs baseline: 1.1073x; 1.1073x over previous
//
#include <hip/hip_runtime.h>
#include <hip/hip_bf16.h>
#include <float.h>

// B=4, S=2048, D=1024 causal attention with input projections.
// out = softmax(mask((q@Wq)(k@Wk)^T / 32)) @ (v@Wv)
//
// Numerics: logits std ~342 -> q/k path uses bf16x2 (hi/lo RTN) split
// arithmetic (3 MFMAs per product). Splits MUST be round-to-nearest
// (truncation = 4x error, failed R2). v path plain bf16.
//
// R5: q/k split hoisted to a memory-bound prepass (R4 was VALU-bound on
// in-loop split8, re-splitting each element 16x). All GEMMs single-buffered
// 2-barrier m97-style (R4 dbuf regressed). Scores stored causal-tile-packed
// (34 MiB) to fit workspace: tile p = ti*(ti+1)/2 + tj, 128x128 fp32.

typedef __attribute__((ext_vector_type(8))) short bf16x8;
typedef __attribute__((ext_vector_type(4))) float f32x4;

#define MFMA16 __builtin_amdgcn_mfma_f32_16x16x32_bf16

union U8 { bf16x8 v; unsigned w[4]; };

__device__ __forceinline__ ushort f2bf(float x) {
  union { float f; unsigned u; } v; v.f = x;
  unsigned r = v.u + 0x7fffu + ((v.u >> 16) & 1u);
  return (ushort)(r >> 16);
}
__device__ __forceinline__ float bf2f(ushort h) {
  union { unsigned u; float f; } v; v.u = ((unsigned)h) << 16;
  return v.f;
}
__device__ __forceinline__ void splitf(float x, ushort& hi, ushort& lo) {
  hi = f2bf(x);
  lo = f2bf(x - bf2f(hi));
}

// Plain fp32 -> bf16x8 (RTN) from 8 consecutive LDS floats (proj_v only).
__device__ __forceinline__ bf16x8 cvt8(const float* lp) {
  U8 H;
#pragma unroll
  for (int p = 0; p < 4; ++p) {
    const unsigned u0 = __float_as_uint(lp[2 * p]);
    const unsigned u1 = __float_as_uint(lp[2 * p + 1]);
    const unsigned r0 = (u0 + 0x7fffu + ((u0 >> 16) & 1u)) >> 16;
    const unsigned r1 = (u1 + 0x7fffu + ((u1 >> 16) & 1u)) & 0xffff0000u;
    H.w[p] = r0 | r1;
  }
  return H.v;
}

// ---------------------------------------------------------------------------
// global_load_lds staging. LDS linear [128][BK] (no pad). Chunk = 1024 B.
// ---------------------------------------------------------------------------
#define GLOAD16(gp, lp)                                                        \
  __builtin_amdgcn_global_load_lds(                                            \
      (const __attribute__((address_space(1))) void*)(gp),                     \
      (__attribute__((address_space(3))) void*)(lp), 16, 0, 0)

// bf16 slab 128 x 32 (8 KB, 8 chunks)
__device__ __forceinline__ void stage_bf16_32(const ushort* g, int pitch,
                                              ushort* lds, int w, int lane) {
#pragma unroll
  for (int i = 0; i < 2; ++i) {
    const int c = w * 2 + i;
    const int row = c * 16 + (lane >> 2);
    const int kp = (lane & 3) * 8;
    GLOAD16(g + (size_t)row * pitch + kp, lds + c * 512);
  }
}
// bf16 slab 128 x 64 (16 KB, 16 chunks)
__device__ __forceinline__ void stage_bf16_64(const ushort* g, int pitch,
                                              ushort* lds, int w, int lane) {
#pragma unroll
  for (int i = 0; i < 4; ++i) {
    const int c = w * 4 + i;
    const int row = c * 8 + (lane >> 3);
    const int kp = (lane & 7) * 8;
    GLOAD16(g + (size_t)row * pitch + kp, lds + c * 512);
  }
}
// fp32 slab 128 x 32 (16 KB, 16 chunks) — proj_v B operand
__device__ __forceinline__ void stage_f32_32(const float* g, int pitch,
                                             float* lds, int w, int lane) {
#pragma unroll
  for (int i = 0; i < 4; ++i) {
    const int c = w * 4 + i;
    const int row = c * 8 + (lane >> 3);
    const int kp = (lane & 7) * 4;
    GLOAD16(g + (size_t)row * pitch + kp, lds + c * 256);
  }
}

// ---------------------------------------------------------------------------
// q/k fp32 -> hi/lo bf16 split prepass (memory-bound, grid-stride).
// ---------------------------------------------------------------------------
__global__ __launch_bounds__(256) void split_pre(
    const float* __restrict__ q, const float* __restrict__ k,
    ushort* __restrict__ qh, ushort* __restrict__ ql,
    ushort* __restrict__ kh, ushort* __restrict__ kl) {
  const float* X = blockIdx.y ? k : q;
  ushort* H = blockIdx.y ? kh : qh;
  ushort* L = blockIdx.y ? kl : ql;
  const int n4 = 2097152;  // 8192*1024/4
  for (int i = blockIdx.x * 256 + threadIdx.x; i < n4; i += 2048 * 256) {
    const float4 x = reinterpret_cast<const float4*>(X)[i];
    ushort h0, l0, h1, l1, h2, l2, h3, l3;
    splitf(x.x, h0, l0); splitf(x.y, h1, l1);
    splitf(x.z, h2, l2); splitf(x.w, h3, l3);
    reinterpret_cast<ushort4*>(H)[i] = ushort4{h0, h1, h2, h3};
    reinterpret_cast<ushort4*>(L)[i] = ushort4{l0, l1, l2, l3};
  }
}

// ---------------------------------------------------------------------------
// W transpose + convert (merged z: 0=Wq split, 1=Wk split, 2=Wv plain).
// ---------------------------------------------------------------------------
__global__ __launch_bounds__(256) void wt_conv(
    const float* __restrict__ W0, const float* __restrict__ W1,
    const float* __restrict__ W2, ushort* __restrict__ Th0,
    ushort* __restrict__ Tl0, ushort* __restrict__ Th1,
    ushort* __restrict__ Tl1, ushort* __restrict__ Th2) {
  __shared__ float t[32][33];
  const int z = blockIdx.z;
  const float* W = z == 0 ? W0 : (z == 1 ? W1 : W2);
  ushort* Th = z == 0 ? Th0 : (z == 1 ? Th1 : Th2);
  ushort* Tl = z == 0 ? Tl0 : (z == 1 ? Tl1 : nullptr);
  const int bx = blockIdx.x, by = blockIdx.y;  // k-tile, n-tile
  const int r = threadIdx.x >> 3, c4 = (threadIdx.x & 7) * 4;
  const float4 x =
      *reinterpret_cast<const float4*>(&W[(size_t)(bx * 32 + r) * 1024 + by * 32 + c4]);
  t[r][c4] = x.x; t[r][c4 + 1] = x.y; t[r][c4 + 2] = x.z; t[r][c4 + 3] = x.w;
  __syncthreads();
  ushort h[4], l[4];
#pragma unroll
  for (int j = 0; j < 4; ++j) splitf(t[c4 + j][r], h[j], l[j]);
  const size_t o = (size_t)(by * 32 + r) * 1024 + bx * 32 + c4;
  *reinterpret_cast<ushort4*>(&Th[o]) = ushort4{h[0], h[1], h[2], h[3]};
  if (Tl)
    *reinterpret_cast<ushort4*>(&Tl[o]) = ushort4{l[0], l[1], l[2], l[3]};
}

// ---------------------------------------------------------------------------
// q/k projection, merged z, pre-split operands both sides. 3 MFMA per tile.
// Single-buffered 2-barrier loop; zero in-loop VALU beyond addressing.
// ---------------------------------------------------------------------------
__global__ __launch_bounds__(256) void proj_qk(
    const ushort* __restrict__ Ah0, const ushort* __restrict__ Al0,
    const ushort* __restrict__ Ah1, const ushort* __restrict__ Al1,
    const ushort* __restrict__ Bh0, const ushort* __restrict__ Bl0,
    const ushort* __restrict__ Bh1, const ushort* __restrict__ Bl1,
    ushort* __restrict__ Oh0, ushort* __restrict__ Ol0,
    ushort* __restrict__ Oh1, ushort* __restrict__ Ol1) {
  __shared__ ushort Ahs[4096], Als[4096], Bhs[4096], Bls[4096];
  const int z = blockIdx.z;
  const ushort* Ah = z ? Ah1 : Ah0;
  const ushort* Al = z ? Al1 : Al0;
  const ushort* Bh = z ? Bh1 : Bh0;
  const ushort* Bl = z ? Bl1 : Bl0;
  ushort* Oh = z ? Oh1 : Oh0;
  ushort* Ol = z ? Ol1 : Ol0;
  const int tid = threadIdx.x, lane = tid & 63, w = tid >> 6;
  const int wr = w >> 1, wc = w & 1;
  const int lr = lane & 15, kg = lane >> 4;
  const int m0 = blockIdx.y * 128, n0 = blockIdx.x * 128;
  f32x4 acc[4][4] = {};

  for (int k0 = 0; k0 < 1024; k0 += 32) {
    stage_bf16_32(Ah + (size_t)m0 * 1024 + k0, 1024, Ahs, w, lane);
    stage_bf16_32(Al + (size_t)m0 * 1024 + k0, 1024, Als, w, lane);
    stage_bf16_32(Bh + (size_t)n0 * 1024 + k0, 1024, Bhs, w, lane);
    stage_bf16_32(Bl + (size_t)n0 * 1024 + k0, 1024, Bls, w, lane);
    __syncthreads();
    bf16x8 ah[4], al[4], bh[4], bl[4];
#pragma unroll
    for (int m = 0; m < 4; ++m) {
      ah[m] = *reinterpret_cast<bf16x8*>(&Ahs[(wr * 64 + m * 16 + lr) * 32 + kg * 8]);
      al[m] = *reinterpret_cast<bf16x8*>(&Als[(wr * 64 + m * 16 + lr) * 32 + kg * 8]);
    }
#pragma unroll
    for (int n = 0; n < 4; ++n) {
      bh[n] = *reinterpret_cast<bf16x8*>(&Bhs[(wc * 64 + n * 16 + lr) * 32 + kg * 8]);
      bl[n] = *reinterpret_cast<bf16x8*>(&Bls[(wc * 64 + n * 16 + lr) * 32 + kg * 8]);
    }
#pragma unroll
    for (int m = 0; m < 4; ++m)
#pragma unroll
      for (int n = 0; n < 4; ++n) {
        acc[m][n] = MFMA16(ah[m], bh[n], acc[m][n], 0, 0, 0);
        acc[m][n] = MFMA16(ah[m], bl[n], acc[m][n], 0, 0, 0);
        acc[m][n] = MFMA16(al[m], bh[n], acc[m][n], 0, 0, 0);
      }
    __syncthreads();
  }
#pragma unroll
  for (int m = 0; m < 4; ++m)
#pragma unroll
    for (int n = 0; n < 4; ++n)
#pragma unroll
      for (int reg = 0; reg < 4; ++reg) {
        const int gm = m0 + wr * 64 + m * 16 + kg * 4 + reg;
        const int gn = n0 + wc * 64 + n * 16 + lr;
        ushort h, l;
        splitf(acc[m][n][reg], h, l);
        Oh[(size_t)gm * 1024 + gn] = h;
        Ol[(size_t)gm * 1024 + gn] = l;
      }
}

// ---------------------------------------------------------------------------
// v projection, transposed output: v1t[b][d][j] = sum_k Wv[k][d] v[b,j,k].
// ---------------------------------------------------------------------------
__global__ __launch_bounds__(256) void proj_v(const ushort* __restrict__ Wvt,
                                              const float* __restrict__ V,
                                              ushort* __restrict__ v1t) {
  __shared__ ushort Ahs[4096];
  __shared__ float Bs[4096];
  const int tid = threadIdx.x, lane = tid & 63, w = tid >> 6;
  const int wr = w >> 1, wc = w & 1;
  const int lr = lane & 15, kg = lane >> 4;
  const int m0 = blockIdx.y * 128;   // d-tile
  const int n0 = blockIdx.x * 128;   // global j tile
  f32x4 acc[4][4] = {};

  for (int k0 = 0; k0 < 1024; k0 += 32) {
    stage_bf16_32(Wvt + (size_t)m0 * 1024 + k0, 1024, Ahs, w, lane);
    stage_f32_32(V + (size_t)n0 * 1024 + k0, 1024, Bs, w, lane);
    __syncthreads();
    bf16x8 ah[4], bh[4];
#pragma unroll
    for (int m = 0; m < 4; ++m)
      ah[m] = *reinterpret_cast<bf16x8*>(&Ahs[(wr * 64 + m * 16 + lr) * 32 + kg * 8]);
#pragma unroll
    for (int n = 0; n < 4; ++n)
      bh[n] = cvt8(&Bs[(wc * 64 + n * 16 + lr) * 32 + kg * 8]);
#pragma unroll
    for (int m = 0; m < 4; ++m)
#pragma unroll
      for (int n = 0; n < 4; ++n)
        acc[m][n] = MFMA16(ah[m], bh[n], acc[m][n], 0, 0, 0);
    __syncthreads();
  }
#pragma unroll
  for (int m = 0; m < 4; ++m)
#pragma unroll
    for (int n = 0; n < 4; ++n)
#pragma unroll
      for (int reg = 0; reg < 4; ++reg) {
        const int gm = m0 + wr * 64 + m * 16 + kg * 4 + reg;  // d
        const int gn = n0 + wc * 64 + n * 16 + lr;            // global j
        const int b = gn >> 11, jj = gn & 2047;
        v1t[((size_t)b << 21) + (size_t)gm * 2048 + jj] = f2bf(acc[m][n][reg]);
      }
}

// ---------------------------------------------------------------------------
// QK^T, bf16x2 split (3 MFMA), causal triangular grid, PACKED tile output:
// tile p = ti*(ti+1)/2 + tj, 128x128 fp32 at (b*136+p)*16384.
// ---------------------------------------------------------------------------
__global__ __launch_bounds__(256) void qk2(
    const ushort* __restrict__ q1h, const ushort* __restrict__ q1l,
    const ushort* __restrict__ k1h, const ushort* __restrict__ k1l,
    float* __restrict__ scores) {
  __shared__ ushort Ahs[4096], Als[4096], Bhs[4096], Bls[4096];
  const int tid = threadIdx.x, lane = tid & 63, w = tid >> 6;
  const int wr = w >> 1, wc = w & 1;
  const int lr = lane & 15, kg = lane >> 4;
  const int b = blockIdx.y;
  int p = blockIdx.x, ti = 0, accp = 0;
  while (accp + ti + 1 <= p) { accp += ti + 1; ++ti; }
  const int tj = p - accp;
  const ushort* qh = q1h + ((size_t)b * 2048 + ti * 128) * 1024;
  const ushort* ql = q1l + ((size_t)b * 2048 + ti * 128) * 1024;
  const ushort* kh = k1h + ((size_t)b * 2048 + tj * 128) * 1024;
  const ushort* kl = k1l + ((size_t)b * 2048 + tj * 128) * 1024;
  f32x4 acc[4][4] = {};

  for (int k0 = 0; k0 < 1024; k0 += 32) {
    stage_bf16_32(qh + k0, 1024, Ahs, w, lane);
    stage_bf16_32(ql + k0, 1024, Als, w, lane);
    stage_bf16_32(kh + k0, 1024, Bhs, w, lane);
    stage_bf16_32(kl + k0, 1024, Bls, w, lane);
    __syncthreads();
    bf16x8 ah[4], al[4], bh[4], bl[4];
#pragma unroll
    for (int m = 0; m < 4; ++m) {
      ah[m] = *reinterpret_cast<bf16x8*>(&Ahs[(wr * 64 + m * 16 + lr) * 32 + kg * 8]);
      al[m] = *reinterpret_cast<bf16x8*>(&Als[(wr * 64 + m * 16 + lr) * 32 + kg * 8]);
    }
#pragma unroll
    for (int n = 0; n < 4; ++n) {
      bh[n] = *reinterpret_cast<bf16x8*>(&Bhs[(wc * 64 + n * 16 + lr) * 32 + kg * 8]);
      bl[n] = *reinterpret_cast<bf16x8*>(&Bls[(wc * 64 + n * 16 + lr) * 32 + kg * 8]);
    }
#pragma unroll
    for (int m = 0; m < 4; ++m)
#pragma unroll
      for (int n = 0; n < 4; ++n) {
        acc[m][n] = MFMA16(ah[m], bh[n], acc[m][n], 0, 0, 0);
        acc[m][n] = MFMA16(ah[m], bl[n], acc[m][n], 0, 0, 0);
        acc[m][n] = MFMA16(al[m], bh[n], acc[m][n], 0, 0, 0);
      }
    __syncthreads();
  }
  const float sc = 0.03125f;  // 1/sqrt(1024)
  float* st = scores + ((size_t)b * 136 + p) * 16384;
  const bool diag = (ti == tj);
#pragma unroll
  for (int m = 0; m < 4; ++m)
#pragma unroll
    for (int n = 0; n < 4; ++n)
#pragma unroll
      for (int reg = 0; reg < 4; ++reg) {
        const int il = wr * 64 + m * 16 + kg * 4 + reg;
        const int jl = wc * 64 + n * 16 + lr;
        float v = acc[m][n][reg] * sc;
        if (diag && jl > il) v = -FLT_MAX;
        st[il * 128 + jl] = v;
      }
}

// ---------------------------------------------------------------------------
// Row softmax over packed tiles; P written bf16 in place within each row's
// own fp32 storage: P(rl,c) at ushort [rl*256 + c] of the tile.
// ---------------------------------------------------------------------------
__global__ __launch_bounds__(256) void softmax_kernel(float* __restrict__ scores) {
  __shared__ float red[8];
  const int rb = blockIdx.x;
  const int b = rb >> 11, r = rb & 2047;
  const int ti = r >> 7, rl = r & 127, ncol = (ti + 1) * 128;
  const int valid = r + 1;
  float* srow = scores + ((size_t)b * 136 + (ti * (ti + 1)) / 2) * 16384;
  const int tid = threadIdx.x, lane = tid & 63, w = tid >> 6;

  float vals[8];
  float mx = -FLT_MAX;
#pragma unroll
  for (int c = 0; c < 8; ++c) {
    const int j = tid + c * 256;
    vals[c] = (j < valid)
                  ? srow[(size_t)(j >> 7) * 16384 + rl * 128 + (j & 127)]
                  : -FLT_MAX;
    mx = fmaxf(mx, vals[c]);
  }
#pragma unroll
  for (int o = 32; o; o >>= 1) mx = fmaxf(mx, __shfl_xor(mx, o));
  if (lane == 0) red[w] = mx;
  __syncthreads();
  mx = fmaxf(fmaxf(red[0], red[1]), fmaxf(red[2], red[3]));

  float ex[8];
  float sum = 0.f;
#pragma unroll
  for (int c = 0; c < 8; ++c) {
    const int j = tid + c * 256;
    ex[c] = (j < valid) ? __expf(vals[c] - mx) : 0.f;
    sum += ex[c];
  }
#pragma unroll
  for (int o = 32; o; o >>= 1) sum += __shfl_xor(sum, o);
  if (lane == 0) red[4 + w] = sum;
  __syncthreads();
  sum = red[4] + red[5] + red[6] + red[7];
  const float inv = 1.f / sum;
#pragma unroll
  for (int c = 0; c < 8; ++c) {
    const int j = tid + c * 256;
    if (j < ncol) {
      ushort* pt = reinterpret_cast<ushort*>(srow + (size_t)(j >> 7) * 16384);
      pt[rl * 256 + (j & 127)] = f2bf(ex[c] * inv);
    }
  }
}

// ---------------------------------------------------------------------------
// PV: out[b,i,:] = P[b,i,:] @ v1. P bf16 in packed tiles (row pitch 256
// ushorts), V from v1t (pitch 2048), BK=64. K ends at (ti+1)*128.
// ---------------------------------------------------------------------------
__global__ __launch_bounds__(256) void pv2(const float* __restrict__ scores,
                                           const ushort* __restrict__ v1t,
                                           float* __restrict__ out) {
  __shared__ ushort Ps[128 * 64], Vs[128 * 64];
  const int tid = threadIdx.x, lane = tid & 63, w = tid >> 6;
  const int wr = w >> 1, wc = w & 1;
  const int lr = lane & 15, kg = lane >> 4;
  const int b = blockIdx.z;
  const int ti = 15 - blockIdx.y;  // long blocks first
  const int n0 = blockIdx.x * 128;
  const int tri_ti = (ti * (ti + 1)) / 2;
  const ushort* vbase = v1t + ((size_t)b << 21) + (size_t)n0 * 2048;
  const int kend = (ti + 1) * 128;
  f32x4 acc[4][4] = {};

  for (int k0 = 0; k0 < kend; k0 += 64) {
    const ushort* pt = reinterpret_cast<const ushort*>(
        scores + ((size_t)b * 136 + tri_ti + (k0 >> 7)) * 16384);
    stage_bf16_64(pt + (k0 & 64), 256, Ps, w, lane);
    stage_bf16_64(vbase + k0, 2048, Vs, w, lane);
    __syncthreads();
#pragma unroll
    for (int t2 = 0; t2 < 2; ++t2) {
      bf16x8 pa[4], vb[4];
#pragma unroll
      for (int m = 0; m < 4; ++m)
        pa[m] = *reinterpret_cast<bf16x8*>(
            &Ps[(wr * 64 + m * 16 + lr) * 64 + t2 * 32 + kg * 8]);
#pragma unroll
      for (int n = 0; n < 4; ++n)
        vb[n] = *reinterpret_cast<bf16x8*>(
            &Vs[(wc * 64 + n * 16 + lr) * 64 + t2 * 32 + kg * 8]);
#pragma unroll
      for (int m = 0; m < 4; ++m)
#pragma unroll
        for (int n = 0; n < 4; ++n)
          acc[m][n] = MFMA16(pa[m], vb[n], acc[m][n], 0, 0, 0);
    }
    __syncthreads();
  }
#pragma unroll
  for (int m = 0; m < 4; ++m)
#pragma unroll
    for (int n = 0; n < 4; ++n)
#pragma unroll
      for (int reg = 0; reg < 4; ++reg) {
        const int gm = ti * 128 + wr * 64 + m * 16 + kg * 4 + reg;
        const int gn = n0 + wc * 64 + n * 16 + lr;
        out[((size_t)b * 2048 + gm) * 1024 + gn] = acc[m][n][reg];
      }
}

extern "C" void kernel_launch(void* const* d_in, const int* in_sizes, int n_in,
                              void* d_out, int out_size, void* d_ws,
                              size_t ws_size, hipStream_t stream) {
  const float* q = (const float*)d_in[0];
  const float* k = (const float*)d_in[1];
  const float* v = (const float*)d_in[2];
  // d_in[3] = causal mask — statically known, ignored.
  const float* Wq = (const float*)d_in[4];
  const float* Wk = (const float*)d_in[5];
  const float* Wv = (const float*)d_in[6];
  float* out = (float*)d_out;

  // Workspace (138 MiB total), liveness-aliased:
  //  [0,64M)    region1: qsplit (qsh,qsl,ksh,ksl 4x16M) during prepass/proj_qk
  //             -> scores_packed [0,34M) from qk2 on; v1t [36M,52M) from proj_v
  //  [64,128M)  q1hi q1lo k1hi k1lo (4x16M)
  //  [128,138M) Wq/Wk transposed hi/lo (8M, dead after proj_qk); Wvt (2M)
  char* ws = (char*)d_ws;
  float* scores = (float*)ws;
  ushort* qsh = (ushort*)ws;            // 16 MiB each
  ushort* qsl = qsh + 8388608;
  ushort* ksh = qsh + 2 * 8388608;
  ushort* ksl = qsh + 3 * 8388608;
  ushort* v1t = (ushort*)(ws + 37748736);   // 16 MiB at 36M
  ushort* q1hi = (ushort*)(ws + 67108864);  // 16 MiB each
  ushort* q1lo = q1hi + 8388608;
  ushort* k1hi = q1hi + 2 * 8388608;
  ushort* k1lo = q1hi + 3 * 8388608;
  ushort* Wqth = (ushort*)(ws + 134217728);  // 2 MiB each
  ushort* Wqtl = Wqth + 1048576;
  ushort* Wkth = Wqth + 2097152;
  ushort* Wktl = Wqth + 3145728;
  ushort* Wvt  = Wqth + 4194304;
  const size_t need = 134217728 + 10485760;  // 144,703,488 (138 MiB)
  if (ws_size < need) return;

  dim3 blk(256);
  wt_conv<<<dim3(32, 32, 3), blk, 0, stream>>>(Wq, Wk, Wv, Wqth, Wqtl, Wkth,
                                               Wktl, Wvt);
  split_pre<<<dim3(2048, 2), blk, 0, stream>>>(q, k, qsh, qsl, ksh, ksl);
  proj_qk<<<dim3(8, 64, 2), blk, 0, stream>>>(qsh, qsl, ksh, ksl, Wqth, Wqtl,
                                              Wkth, Wktl, q1hi, q1lo, k1hi,
                                              k1lo);
  proj_v<<<dim3(64, 8), blk, 0, stream>>>(Wvt, v, v1t);
  qk2<<<dim3(136, 4), blk, 0, stream>>>(q1hi, q1lo, k1hi, k1lo, scores);
  softmax_kernel<<<dim3(8192), blk, 0, stream>>>(scores);
  pv2<<<dim3(8, 16, 4), blk, 0, stream>>>(scores, v1t, out);
}

// Round 6
// 350.618 us; speedup vs baseline: 1.1364x; 1.0263x over previous
//
#include <hip/hip_runtime.h>
#include <hip/hip_bf16.h>
#include <float.h>

// B=4, S=2048, D=1024 causal attention with input projections.
// out = softmax(mask((q@Wq)(k@Wk)^T / 32)) @ (v@Wv)
//
// Numerics: logits std ~342 -> q/k path uses bf16x2 (hi/lo RTN) split
// arithmetic (3 MFMAs per product). Splits MUST be round-to-nearest
// (truncation = 4x error, failed R2). v path plain bf16.
//
// R6: qk2 split-K (z halves of K=1024 -> 1088 blocks, 4.25/CU) to fix its
// grid starvation (544 blocks = 2.1/CU ran at 520 TF vs proj_qk's 820 at
// 4/CU). Partial scores summed in softmax. Causal mask writes removed from
// qk2 (dead: softmax reads only j<valid and zero-fills P beyond).

typedef __attribute__((ext_vector_type(8))) short bf16x8;
typedef __attribute__((ext_vector_type(4))) float f32x4;

#define MFMA16 __builtin_amdgcn_mfma_f32_16x16x32_bf16

union U8 { bf16x8 v; unsigned w[4]; };

__device__ __forceinline__ ushort f2bf(float x) {
  union { float f; unsigned u; } v; v.f = x;
  unsigned r = v.u + 0x7fffu + ((v.u >> 16) & 1u);
  return (ushort)(r >> 16);
}
__device__ __forceinline__ float bf2f(ushort h) {
  union { unsigned u; float f; } v; v.u = ((unsigned)h) << 16;
  return v.f;
}
__device__ __forceinline__ void splitf(float x, ushort& hi, ushort& lo) {
  hi = f2bf(x);
  lo = f2bf(x - bf2f(hi));
}

// Plain fp32 -> bf16x8 (RTN) from 8 consecutive LDS floats (proj_v only).
__device__ __forceinline__ bf16x8 cvt8(const float* lp) {
  U8 H;
#pragma unroll
  for (int p = 0; p < 4; ++p) {
    const unsigned u0 = __float_as_uint(lp[2 * p]);
    const unsigned u1 = __float_as_uint(lp[2 * p + 1]);
    const unsigned r0 = (u0 + 0x7fffu + ((u0 >> 16) & 1u)) >> 16;
    const unsigned r1 = (u1 + 0x7fffu + ((u1 >> 16) & 1u)) & 0xffff0000u;
    H.w[p] = r0 | r1;
  }
  return H.v;
}

// ---------------------------------------------------------------------------
// global_load_lds staging. LDS linear [128][BK] (no pad). Chunk = 1024 B.
// ---------------------------------------------------------------------------
#define GLOAD16(gp, lp)                                                        \
  __builtin_amdgcn_global_load_lds(                                            \
      (const __attribute__((address_space(1))) void*)(gp),                     \
      (__attribute__((address_space(3))) void*)(lp), 16, 0, 0)

// bf16 slab 128 x 32 (8 KB, 8 chunks)
__device__ __forceinline__ void stage_bf16_32(const ushort* g, int pitch,
                                              ushort* lds, int w, int lane) {
#pragma unroll
  for (int i = 0; i < 2; ++i) {
    const int c = w * 2 + i;
    const int row = c * 16 + (lane >> 2);
    const int kp = (lane & 3) * 8;
    GLOAD16(g + (size_t)row * pitch + kp, lds + c * 512);
  }
}
// bf16 slab 128 x 64 (16 KB, 16 chunks)
__device__ __forceinline__ void stage_bf16_64(const ushort* g, int pitch,
                                              ushort* lds, int w, int lane) {
#pragma unroll
  for (int i = 0; i < 4; ++i) {
    const int c = w * 4 + i;
    const int row = c * 8 + (lane >> 3);
    const int kp = (lane & 7) * 8;
    GLOAD16(g + (size_t)row * pitch + kp, lds + c * 512);
  }
}
// fp32 slab 128 x 32 (16 KB, 16 chunks) — proj_v B operand
__device__ __forceinline__ void stage_f32_32(const float* g, int pitch,
                                             float* lds, int w, int lane) {
#pragma unroll
  for (int i = 0; i < 4; ++i) {
    const int c = w * 4 + i;
    const int row = c * 8 + (lane >> 3);
    const int kp = (lane & 7) * 4;
    GLOAD16(g + (size_t)row * pitch + kp, lds + c * 256);
  }
}

// ---------------------------------------------------------------------------
// q/k fp32 -> hi/lo bf16 split prepass (memory-bound, grid-stride).
// ---------------------------------------------------------------------------
__global__ __launch_bounds__(256) void split_pre(
    const float* __restrict__ q, const float* __restrict__ k,
    ushort* __restrict__ qh, ushort* __restrict__ ql,
    ushort* __restrict__ kh, ushort* __restrict__ kl) {
  const float* X = blockIdx.y ? k : q;
  ushort* H = blockIdx.y ? kh : qh;
  ushort* L = blockIdx.y ? kl : ql;
  const int n4 = 2097152;  // 8192*1024/4
  for (int i = blockIdx.x * 256 + threadIdx.x; i < n4; i += 2048 * 256) {
    const float4 x = reinterpret_cast<const float4*>(X)[i];
    ushort h0, l0, h1, l1, h2, l2, h3, l3;
    splitf(x.x, h0, l0); splitf(x.y, h1, l1);
    splitf(x.z, h2, l2); splitf(x.w, h3, l3);
    reinterpret_cast<ushort4*>(H)[i] = ushort4{h0, h1, h2, h3};
    reinterpret_cast<ushort4*>(L)[i] = ushort4{l0, l1, l2, l3};
  }
}

// ---------------------------------------------------------------------------
// W transpose + convert (merged z: 0=Wq split, 1=Wk split, 2=Wv plain).
// ---------------------------------------------------------------------------
__global__ __launch_bounds__(256) void wt_conv(
    const float* __restrict__ W0, const float* __restrict__ W1,
    const float* __restrict__ W2, ushort* __restrict__ Th0,
    ushort* __restrict__ Tl0, ushort* __restrict__ Th1,
    ushort* __restrict__ Tl1, ushort* __restrict__ Th2) {
  __shared__ float t[32][33];
  const int z = blockIdx.z;
  const float* W = z == 0 ? W0 : (z == 1 ? W1 : W2);
  ushort* Th = z == 0 ? Th0 : (z == 1 ? Th1 : Th2);
  ushort* Tl = z == 0 ? Tl0 : (z == 1 ? Tl1 : nullptr);
  const int bx = blockIdx.x, by = blockIdx.y;  // k-tile, n-tile
  const int r = threadIdx.x >> 3, c4 = (threadIdx.x & 7) * 4;
  const float4 x =
      *reinterpret_cast<const float4*>(&W[(size_t)(bx * 32 + r) * 1024 + by * 32 + c4]);
  t[r][c4] = x.x; t[r][c4 + 1] = x.y; t[r][c4 + 2] = x.z; t[r][c4 + 3] = x.w;
  __syncthreads();
  ushort h[4], l[4];
#pragma unroll
  for (int j = 0; j < 4; ++j) splitf(t[c4 + j][r], h[j], l[j]);
  const size_t o = (size_t)(by * 32 + r) * 1024 + bx * 32 + c4;
  *reinterpret_cast<ushort4*>(&Th[o]) = ushort4{h[0], h[1], h[2], h[3]};
  if (Tl)
    *reinterpret_cast<ushort4*>(&Tl[o]) = ushort4{l[0], l[1], l[2], l[3]};
}

// ---------------------------------------------------------------------------
// q/k projection, merged z, pre-split operands both sides. 3 MFMA per tile.
// Single-buffered 2-barrier loop; zero in-loop VALU beyond addressing.
// ---------------------------------------------------------------------------
__global__ __launch_bounds__(256) void proj_qk(
    const ushort* __restrict__ Ah0, const ushort* __restrict__ Al0,
    const ushort* __restrict__ Ah1, const ushort* __restrict__ Al1,
    const ushort* __restrict__ Bh0, const ushort* __restrict__ Bl0,
    const ushort* __restrict__ Bh1, const ushort* __restrict__ Bl1,
    ushort* __restrict__ Oh0, ushort* __restrict__ Ol0,
    ushort* __restrict__ Oh1, ushort* __restrict__ Ol1) {
  __shared__ ushort Ahs[4096], Als[4096], Bhs[4096], Bls[4096];
  const int z = blockIdx.z;
  const ushort* Ah = z ? Ah1 : Ah0;
  const ushort* Al = z ? Al1 : Al0;
  const ushort* Bh = z ? Bh1 : Bh0;
  const ushort* Bl = z ? Bl1 : Bl0;
  ushort* Oh = z ? Oh1 : Oh0;
  ushort* Ol = z ? Ol1 : Ol0;
  const int tid = threadIdx.x, lane = tid & 63, w = tid >> 6;
  const int wr = w >> 1, wc = w & 1;
  const int lr = lane & 15, kg = lane >> 4;
  const int m0 = blockIdx.y * 128, n0 = blockIdx.x * 128;
  f32x4 acc[4][4] = {};

  for (int k0 = 0; k0 < 1024; k0 += 32) {
    stage_bf16_32(Ah + (size_t)m0 * 1024 + k0, 1024, Ahs, w, lane);
    stage_bf16_32(Al + (size_t)m0 * 1024 + k0, 1024, Als, w, lane);
    stage_bf16_32(Bh + (size_t)n0 * 1024 + k0, 1024, Bhs, w, lane);
    stage_bf16_32(Bl + (size_t)n0 * 1024 + k0, 1024, Bls, w, lane);
    __syncthreads();
    bf16x8 ah[4], al[4], bh[4], bl[4];
#pragma unroll
    for (int m = 0; m < 4; ++m) {
      ah[m] = *reinterpret_cast<bf16x8*>(&Ahs[(wr * 64 + m * 16 + lr) * 32 + kg * 8]);
      al[m] = *reinterpret_cast<bf16x8*>(&Als[(wr * 64 + m * 16 + lr) * 32 + kg * 8]);
    }
#pragma unroll
    for (int n = 0; n < 4; ++n) {
      bh[n] = *reinterpret_cast<bf16x8*>(&Bhs[(wc * 64 + n * 16 + lr) * 32 + kg * 8]);
      bl[n] = *reinterpret_cast<bf16x8*>(&Bls[(wc * 64 + n * 16 + lr) * 32 + kg * 8]);
    }
#pragma unroll
    for (int m = 0; m < 4; ++m)
#pragma unroll
      for (int n = 0; n < 4; ++n) {
        acc[m][n] = MFMA16(ah[m], bh[n], acc[m][n], 0, 0, 0);
        acc[m][n] = MFMA16(ah[m], bl[n], acc[m][n], 0, 0, 0);
        acc[m][n] = MFMA16(al[m], bh[n], acc[m][n], 0, 0, 0);
      }
    __syncthreads();
  }
#pragma unroll
  for (int m = 0; m < 4; ++m)
#pragma unroll
    for (int n = 0; n < 4; ++n)
#pragma unroll
      for (int reg = 0; reg < 4; ++reg) {
        const int gm = m0 + wr * 64 + m * 16 + kg * 4 + reg;
        const int gn = n0 + wc * 64 + n * 16 + lr;
        ushort h, l;
        splitf(acc[m][n][reg], h, l);
        Oh[(size_t)gm * 1024 + gn] = h;
        Ol[(size_t)gm * 1024 + gn] = l;
      }
}

// ---------------------------------------------------------------------------
// v projection, transposed output: v1t[b][d][j] = sum_k Wv[k][d] v[b,j,k].
// ---------------------------------------------------------------------------
__global__ __launch_bounds__(256) void proj_v(const ushort* __restrict__ Wvt,
                                              const float* __restrict__ V,
                                              ushort* __restrict__ v1t) {
  __shared__ ushort Ahs[4096];
  __shared__ float Bs[4096];
  const int tid = threadIdx.x, lane = tid & 63, w = tid >> 6;
  const int wr = w >> 1, wc = w & 1;
  const int lr = lane & 15, kg = lane >> 4;
  const int m0 = blockIdx.y * 128;   // d-tile
  const int n0 = blockIdx.x * 128;   // global j tile
  f32x4 acc[4][4] = {};

  for (int k0 = 0; k0 < 1024; k0 += 32) {
    stage_bf16_32(Wvt + (size_t)m0 * 1024 + k0, 1024, Ahs, w, lane);
    stage_f32_32(V + (size_t)n0 * 1024 + k0, 1024, Bs, w, lane);
    __syncthreads();
    bf16x8 ah[4], bh[4];
#pragma unroll
    for (int m = 0; m < 4; ++m)
      ah[m] = *reinterpret_cast<bf16x8*>(&Ahs[(wr * 64 + m * 16 + lr) * 32 + kg * 8]);
#pragma unroll
    for (int n = 0; n < 4; ++n)
      bh[n] = cvt8(&Bs[(wc * 64 + n * 16 + lr) * 32 + kg * 8]);
#pragma unroll
    for (int m = 0; m < 4; ++m)
#pragma unroll
      for (int n = 0; n < 4; ++n)
        acc[m][n] = MFMA16(ah[m], bh[n], acc[m][n], 0, 0, 0);
    __syncthreads();
  }
#pragma unroll
  for (int m = 0; m < 4; ++m)
#pragma unroll
    for (int n = 0; n < 4; ++n)
#pragma unroll
      for (int reg = 0; reg < 4; ++reg) {
        const int gm = m0 + wr * 64 + m * 16 + kg * 4 + reg;  // d
        const int gn = n0 + wc * 64 + n * 16 + lr;            // global j
        const int b = gn >> 11, jj = gn & 2047;
        v1t[((size_t)b << 21) + (size_t)gm * 2048 + jj] = f2bf(acc[m][n][reg]);
      }
}

// ---------------------------------------------------------------------------
// QK^T, bf16x2 split (3 MFMA), causal triangular grid, SPLIT-K over
// blockIdx.z (K halves of 512). Packed tile output: tile p = ti*(ti+1)/2+tj,
// 128x128 fp32 at (b*136+p)*16384 of scoresA (z=0) / scoresB (z=1).
// No masking (softmax reads only j<=row and zero-fills P beyond).
// ---------------------------------------------------------------------------
__global__ __launch_bounds__(256) void qk2(
    const ushort* __restrict__ q1h, const ushort* __restrict__ q1l,
    const ushort* __restrict__ k1h, const ushort* __restrict__ k1l,
    float* __restrict__ scoresA, float* __restrict__ scoresB) {
  __shared__ ushort Ahs[4096], Als[4096], Bhs[4096], Bls[4096];
  const int tid = threadIdx.x, lane = tid & 63, w = tid >> 6;
  const int wr = w >> 1, wc = w & 1;
  const int lr = lane & 15, kg = lane >> 4;
  const int b = blockIdx.y;
  const int kh0 = blockIdx.z * 512;  // K half
  int p = blockIdx.x, ti = 0, accp = 0;
  while (accp + ti + 1 <= p) { accp += ti + 1; ++ti; }
  const int tj = p - accp;
  const ushort* qh = q1h + ((size_t)b * 2048 + ti * 128) * 1024 + kh0;
  const ushort* ql = q1l + ((size_t)b * 2048 + ti * 128) * 1024 + kh0;
  const ushort* kh = k1h + ((size_t)b * 2048 + tj * 128) * 1024 + kh0;
  const ushort* kl = k1l + ((size_t)b * 2048 + tj * 128) * 1024 + kh0;
  f32x4 acc[4][4] = {};

  for (int k0 = 0; k0 < 512; k0 += 32) {
    stage_bf16_32(qh + k0, 1024, Ahs, w, lane);
    stage_bf16_32(ql + k0, 1024, Als, w, lane);
    stage_bf16_32(kh + k0, 1024, Bhs, w, lane);
    stage_bf16_32(kl + k0, 1024, Bls, w, lane);
    __syncthreads();
    bf16x8 ah[4], al[4], bh[4], bl[4];
#pragma unroll
    for (int m = 0; m < 4; ++m) {
      ah[m] = *reinterpret_cast<bf16x8*>(&Ahs[(wr * 64 + m * 16 + lr) * 32 + kg * 8]);
      al[m] = *reinterpret_cast<bf16x8*>(&Als[(wr * 64 + m * 16 + lr) * 32 + kg * 8]);
    }
#pragma unroll
    for (int n = 0; n < 4; ++n) {
      bh[n] = *reinterpret_cast<bf16x8*>(&Bhs[(wc * 64 + n * 16 + lr) * 32 + kg * 8]);
      bl[n] = *reinterpret_cast<bf16x8*>(&Bls[(wc * 64 + n * 16 + lr) * 32 + kg * 8]);
    }
#pragma unroll
    for (int m = 0; m < 4; ++m)
#pragma unroll
      for (int n = 0; n < 4; ++n) {
        acc[m][n] = MFMA16(ah[m], bh[n], acc[m][n], 0, 0, 0);
        acc[m][n] = MFMA16(ah[m], bl[n], acc[m][n], 0, 0, 0);
        acc[m][n] = MFMA16(al[m], bh[n], acc[m][n], 0, 0, 0);
      }
    __syncthreads();
  }
  const float sc = 0.03125f;  // 1/sqrt(1024)
  float* st = (blockIdx.z ? scoresB : scoresA) + ((size_t)b * 136 + p) * 16384;
#pragma unroll
  for (int m = 0; m < 4; ++m)
#pragma unroll
    for (int n = 0; n < 4; ++n)
#pragma unroll
      for (int reg = 0; reg < 4; ++reg) {
        const int il = wr * 64 + m * 16 + kg * 4 + reg;
        const int jl = wc * 64 + n * 16 + lr;
        st[il * 128 + jl] = acc[m][n][reg] * sc;
      }
}

// ---------------------------------------------------------------------------
// Row softmax over packed tiles, merging the two split-K partials.
// P written bf16 in place over scoresA: P(rl,c) at ushort [rl*256+c] of tile.
// ---------------------------------------------------------------------------
__global__ __launch_bounds__(256) void softmax_kernel(
    float* __restrict__ scoresA, const float* __restrict__ scoresB) {
  __shared__ float red[8];
  const int rb = blockIdx.x;
  const int b = rb >> 11, r = rb & 2047;
  const int ti = r >> 7, rl = r & 127, ncol = (ti + 1) * 128;
  const int valid = r + 1;
  const size_t tbase = ((size_t)b * 136 + (ti * (ti + 1)) / 2) * 16384;
  float* srowA = scoresA + tbase;
  const float* srowB = scoresB + tbase;
  const int tid = threadIdx.x, lane = tid & 63, w = tid >> 6;

  float vals[8];
  float mx = -FLT_MAX;
#pragma unroll
  for (int c = 0; c < 8; ++c) {
    const int j = tid + c * 256;
    const size_t o = (size_t)(j >> 7) * 16384 + rl * 128 + (j & 127);
    vals[c] = (j < valid) ? (srowA[o] + srowB[o]) : -FLT_MAX;
    mx = fmaxf(mx, vals[c]);
  }
#pragma unroll
  for (int o = 32; o; o >>= 1) mx = fmaxf(mx, __shfl_xor(mx, o));
  if (lane == 0) red[w] = mx;
  __syncthreads();
  mx = fmaxf(fmaxf(red[0], red[1]), fmaxf(red[2], red[3]));

  float ex[8];
  float sum = 0.f;
#pragma unroll
  for (int c = 0; c < 8; ++c) {
    const int j = tid + c * 256;
    ex[c] = (j < valid) ? __expf(vals[c] - mx) : 0.f;
    sum += ex[c];
  }
#pragma unroll
  for (int o = 32; o; o >>= 1) sum += __shfl_xor(sum, o);
  if (lane == 0) red[4 + w] = sum;
  __syncthreads();
  sum = red[4] + red[5] + red[6] + red[7];
  const float inv = 1.f / sum;
#pragma unroll
  for (int c = 0; c < 8; ++c) {
    const int j = tid + c * 256;
    if (j < ncol) {
      ushort* pt = reinterpret_cast<ushort*>(srowA + (size_t)(j >> 7) * 16384);
      pt[rl * 256 + (j & 127)] = f2bf(ex[c] * inv);
    }
  }
}

// ---------------------------------------------------------------------------
// PV: out[b,i,:] = P[b,i,:] @ v1. P bf16 in packed tiles (row pitch 256
// ushorts), V from v1t (pitch 2048), BK=64. K ends at (ti+1)*128.
// ---------------------------------------------------------------------------
__global__ __launch_bounds__(256) void pv2(const float* __restrict__ scores,
                                           const ushort* __restrict__ v1t,
                                           float* __restrict__ out) {
  __shared__ ushort Ps[128 * 64], Vs[128 * 64];
  const int tid = threadIdx.x, lane = tid & 63, w = tid >> 6;
  const int wr = w >> 1, wc = w & 1;
  const int lr = lane & 15, kg = lane >> 4;
  const int b = blockIdx.z;
  const int ti = 15 - blockIdx.y;  // long blocks first
  const int n0 = blockIdx.x * 128;
  const int tri_ti = (ti * (ti + 1)) / 2;
  const ushort* vbase = v1t + ((size_t)b << 21) + (size_t)n0 * 2048;
  const int kend = (ti + 1) * 128;
  f32x4 acc[4][4] = {};

  for (int k0 = 0; k0 < kend; k0 += 64) {
    const ushort* pt = reinterpret_cast<const ushort*>(
        scores + ((size_t)b * 136 + tri_ti + (k0 >> 7)) * 16384);
    stage_bf16_64(pt + (k0 & 64), 256, Ps, w, lane);
    stage_bf16_64(vbase + k0, 2048, Vs, w, lane);
    __syncthreads();
#pragma unroll
    for (int t2 = 0; t2 < 2; ++t2) {
      bf16x8 pa[4], vb[4];
#pragma unroll
      for (int m = 0; m < 4; ++m)
        pa[m] = *reinterpret_cast<bf16x8*>(
            &Ps[(wr * 64 + m * 16 + lr) * 64 + t2 * 32 + kg * 8]);
#pragma unroll
      for (int n = 0; n < 4; ++n)
        vb[n] = *reinterpret_cast<bf16x8*>(
            &Vs[(wc * 64 + n * 16 + lr) * 64 + t2 * 32 + kg * 8]);
#pragma unroll
      for (int m = 0; m < 4; ++m)
#pragma unroll
        for (int n = 0; n < 4; ++n)
          acc[m][n] = MFMA16(pa[m], vb[n], acc[m][n], 0, 0, 0);
    }
    __syncthreads();
  }
#pragma unroll
  for (int m = 0; m < 4; ++m)
#pragma unroll
    for (int n = 0; n < 4; ++n)
#pragma unroll
      for (int reg = 0; reg < 4; ++reg) {
        const int gm = ti * 128 + wr * 64 + m * 16 + kg * 4 + reg;
        const int gn = n0 + wc * 64 + n * 16 + lr;
        out[((size_t)b * 2048 + gm) * 1024 + gn] = acc[m][n][reg];
      }
}

extern "C" void kernel_launch(void* const* d_in, const int* in_sizes, int n_in,
                              void* d_out, int out_size, void* d_ws,
                              size_t ws_size, hipStream_t stream) {
  const float* q = (const float*)d_in[0];
  const float* k = (const float*)d_in[1];
  const float* v = (const float*)d_in[2];
  // d_in[3] = causal mask — statically known, ignored.
  const float* Wq = (const float*)d_in[4];
  const float* Wk = (const float*)d_in[5];
  const float* Wv = (const float*)d_in[6];
  float* out = (float*)d_out;

  // Workspace (148.9 MB), liveness-aliased:
  //  [0, 71.3M)       qsh,qsl,ksh,ksl (64MB, dead after proj_qk)
  //                   -> scoresA [0,34M), scoresB [34,68M) from qk2 on
  //  [71.3, 138.4M)   q1hi q1lo k1hi k1lo (4x16M, dead after qk2)
  //                   -> v1t [71.3, 88.1M) from proj_v (runs after softmax)
  //  [138.4, 148.9M)  Wq/Wk transposed hi/lo (8M, dead after proj_qk); Wvt
  char* ws = (char*)d_ws;
  const size_t SCORES_T = 35651584;  // 4*136*16384*4
  float* scoresA = (float*)ws;
  float* scoresB = (float*)(ws + SCORES_T);
  ushort* qsh = (ushort*)ws;  // 16 MiB each, alias scores region
  ushort* qsl = qsh + 8388608;
  ushort* ksh = qsh + 2 * 8388608;
  ushort* ksl = qsh + 3 * 8388608;
  ushort* q1hi = (ushort*)(ws + 2 * SCORES_T);  // 16 MiB each
  ushort* q1lo = q1hi + 8388608;
  ushort* k1hi = q1hi + 2 * 8388608;
  ushort* k1lo = q1hi + 3 * 8388608;
  ushort* v1t = (ushort*)(ws + 2 * SCORES_T);  // aliases q1hi/q1lo (dead)
  ushort* Wqth = (ushort*)(ws + 2 * SCORES_T + 67108864);  // 2 MiB each
  ushort* Wqtl = Wqth + 1048576;
  ushort* Wkth = Wqth + 2097152;
  ushort* Wktl = Wqth + 3145728;
  ushort* Wvt  = Wqth + 4194304;
  const size_t need = 2 * SCORES_T + 67108864 + 10485760;  // 148,897,792
  if (ws_size < need) return;

  dim3 blk(256);
  wt_conv<<<dim3(32, 32, 3), blk, 0, stream>>>(Wq, Wk, Wv, Wqth, Wqtl, Wkth,
                                               Wktl, Wvt);
  split_pre<<<dim3(2048, 2), blk, 0, stream>>>(q, k, qsh, qsl, ksh, ksl);
  proj_qk<<<dim3(8, 64, 2), blk, 0, stream>>>(qsh, qsl, ksh, ksl, Wqth, Wqtl,
                                              Wkth, Wktl, q1hi, q1lo, k1hi,
                                              k1lo);
  qk2<<<dim3(136, 4, 2), blk, 0, stream>>>(q1hi, q1lo, k1hi, k1lo, scoresA,
                                           scoresB);
  softmax_kernel<<<dim3(8192), blk, 0, stream>>>(scoresA, scoresB);
  proj_v<<<dim3(64, 8), blk, 0, stream>>>(Wvt, v, v1t);
  pv2<<<dim3(8, 16, 4), blk, 0, stream>>>(scoresA, v1t, out);
}

// Round 7
// 314.885 us; speedup vs baseline: 1.2654x; 1.1135x over previous
//
#include <hip/hip_runtime.h>
#include <hip/hip_bf16.h>
#include <float.h>

// B=4, S=2048, D=1024 causal attention with input projections.
// out = softmax(mask((q@Wq)(k@Wk)^T / 32)) @ (v@Wv)
//
// Numerics: logits std ~342 -> q/k path uses bf16x2 (hi/lo RTN) split
// arithmetic (3 MFMAs per product), ~2^-18 effective. RTN mandatory
// (truncation split = 4x error, failed R2). v path plain bf16.
//
// R7: XCD-aware block swizzles (T1) on all tiled kernels — operand-sharing
// blocks co-located on one XCD's L2 (proj_qk FETCH was 267MB vs ~72MB ideal
// because 8 A-slab sharers were round-robined across XCDs). Softmax
// vectorized (float4 loads / ushort4 stores).

typedef __attribute__((ext_vector_type(8))) short bf16x8;
typedef __attribute__((ext_vector_type(4))) float f32x4;

#define MFMA16 __builtin_amdgcn_mfma_f32_16x16x32_bf16

union U8 { bf16x8 v; unsigned w[4]; };

__device__ __forceinline__ ushort f2bf(float x) {
  union { float f; unsigned u; } v; v.f = x;
  unsigned r = v.u + 0x7fffu + ((v.u >> 16) & 1u);
  return (ushort)(r >> 16);
}
__device__ __forceinline__ float bf2f(ushort h) {
  union { unsigned u; float f; } v; v.u = ((unsigned)h) << 16;
  return v.f;
}
__device__ __forceinline__ void splitf(float x, ushort& hi, ushort& lo) {
  hi = f2bf(x);
  lo = f2bf(x - bf2f(hi));
}

// Plain fp32 -> bf16x8 (RTN) from 8 consecutive LDS floats (proj_v only).
__device__ __forceinline__ bf16x8 cvt8(const float* lp) {
  U8 H;
#pragma unroll
  for (int p = 0; p < 4; ++p) {
    const unsigned u0 = __float_as_uint(lp[2 * p]);
    const unsigned u1 = __float_as_uint(lp[2 * p + 1]);
    const unsigned r0 = (u0 + 0x7fffu + ((u0 >> 16) & 1u)) >> 16;
    const unsigned r1 = (u1 + 0x7fffu + ((u1 >> 16) & 1u)) & 0xffff0000u;
    H.w[p] = r0 | r1;
  }
  return H.v;
}

// ---------------------------------------------------------------------------
// global_load_lds staging. LDS linear [128][BK] (no pad). Chunk = 1024 B.
// ---------------------------------------------------------------------------
#define GLOAD16(gp, lp)                                                        \
  __builtin_amdgcn_global_load_lds(                                            \
      (const __attribute__((address_space(1))) void*)(gp),                     \
      (__attribute__((address_space(3))) void*)(lp), 16, 0, 0)

// bf16 slab 128 x 32 (8 KB, 8 chunks)
__device__ __forceinline__ void stage_bf16_32(const ushort* g, int pitch,
                                              ushort* lds, int w, int lane) {
#pragma unroll
  for (int i = 0; i < 2; ++i) {
    const int c = w * 2 + i;
    const int row = c * 16 + (lane >> 2);
    const int kp = (lane & 3) * 8;
    GLOAD16(g + (size_t)row * pitch + kp, lds + c * 512);
  }
}
// bf16 slab 128 x 64 (16 KB, 16 chunks)
__device__ __forceinline__ void stage_bf16_64(const ushort* g, int pitch,
                                              ushort* lds, int w, int lane) {
#pragma unroll
  for (int i = 0; i < 4; ++i) {
    const int c = w * 4 + i;
    const int row = c * 8 + (lane >> 3);
    const int kp = (lane & 7) * 8;
    GLOAD16(g + (size_t)row * pitch + kp, lds + c * 512);
  }
}
// fp32 slab 128 x 32 (16 KB, 16 chunks) — proj_v B operand
__device__ __forceinline__ void stage_f32_32(const float* g, int pitch,
                                             float* lds, int w, int lane) {
#pragma unroll
  for (int i = 0; i < 4; ++i) {
    const int c = w * 4 + i;
    const int row = c * 8 + (lane >> 3);
    const int kp = (lane & 7) * 4;
    GLOAD16(g + (size_t)row * pitch + kp, lds + c * 256);
  }
}

// ---------------------------------------------------------------------------
// q/k fp32 -> hi/lo bf16 split prepass (memory-bound, grid-stride).
// ---------------------------------------------------------------------------
__global__ __launch_bounds__(256) void split_pre(
    const float* __restrict__ q, const float* __restrict__ k,
    ushort* __restrict__ qh, ushort* __restrict__ ql,
    ushort* __restrict__ kh, ushort* __restrict__ kl) {
  const float* X = blockIdx.y ? k : q;
  ushort* H = blockIdx.y ? kh : qh;
  ushort* L = blockIdx.y ? kl : ql;
  const int n4 = 2097152;  // 8192*1024/4
  for (int i = blockIdx.x * 256 + threadIdx.x; i < n4; i += 2048 * 256) {
    const float4 x = reinterpret_cast<const float4*>(X)[i];
    ushort h0, l0, h1, l1, h2, l2, h3, l3;
    splitf(x.x, h0, l0); splitf(x.y, h1, l1);
    splitf(x.z, h2, l2); splitf(x.w, h3, l3);
    reinterpret_cast<ushort4*>(H)[i] = ushort4{h0, h1, h2, h3};
    reinterpret_cast<ushort4*>(L)[i] = ushort4{l0, l1, l2, l3};
  }
}

// ---------------------------------------------------------------------------
// W transpose + convert (merged z: 0=Wq split, 1=Wk split, 2=Wv plain).
// ---------------------------------------------------------------------------
__global__ __launch_bounds__(256) void wt_conv(
    const float* __restrict__ W0, const float* __restrict__ W1,
    const float* __restrict__ W2, ushort* __restrict__ Th0,
    ushort* __restrict__ Tl0, ushort* __restrict__ Th1,
    ushort* __restrict__ Tl1, ushort* __restrict__ Th2) {
  __shared__ float t[32][33];
  const int z = blockIdx.z;
  const float* W = z == 0 ? W0 : (z == 1 ? W1 : W2);
  ushort* Th = z == 0 ? Th0 : (z == 1 ? Th1 : Th2);
  ushort* Tl = z == 0 ? Tl0 : (z == 1 ? Tl1 : nullptr);
  const int bx = blockIdx.x, by = blockIdx.y;  // k-tile, n-tile
  const int r = threadIdx.x >> 3, c4 = (threadIdx.x & 7) * 4;
  const float4 x =
      *reinterpret_cast<const float4*>(&W[(size_t)(bx * 32 + r) * 1024 + by * 32 + c4]);
  t[r][c4] = x.x; t[r][c4 + 1] = x.y; t[r][c4 + 2] = x.z; t[r][c4 + 3] = x.w;
  __syncthreads();
  ushort h[4], l[4];
#pragma unroll
  for (int j = 0; j < 4; ++j) splitf(t[c4 + j][r], h[j], l[j]);
  const size_t o = (size_t)(by * 32 + r) * 1024 + bx * 32 + c4;
  *reinterpret_cast<ushort4*>(&Th[o]) = ushort4{h[0], h[1], h[2], h[3]};
  if (Tl)
    *reinterpret_cast<ushort4*>(&Tl[o]) = ushort4{l[0], l[1], l[2], l[3]};
}

// ---------------------------------------------------------------------------
// q/k projection, pre-split operands both sides, 3 MFMA per tile pair.
// Flat grid 1024 with XCD swizzle: the 8 n-blocks sharing one A-slab all get
// wgid == same (mod 8) -> same XCD -> slab fetched once into that L2.
//   x(n-tile) = (f>>3)&7 ; r = (f&7)+8*(f>>6) ; y(m-tile) = r&63 ; z = r>>6
// ---------------------------------------------------------------------------
__global__ __launch_bounds__(256) void proj_qk(
    const ushort* __restrict__ Ah0, const ushort* __restrict__ Al0,
    const ushort* __restrict__ Ah1, const ushort* __restrict__ Al1,
    const ushort* __restrict__ Bh0, const ushort* __restrict__ Bl0,
    const ushort* __restrict__ Bh1, const ushort* __restrict__ Bl1,
    ushort* __restrict__ Oh0, ushort* __restrict__ Ol0,
    ushort* __restrict__ Oh1, ushort* __restrict__ Ol1) {
  __shared__ ushort Ahs[4096], Als[4096], Bhs[4096], Bls[4096];
  const int f = blockIdx.x;
  const int xb = (f >> 3) & 7;
  const int r = (f & 7) + ((f >> 6) << 3);
  const int yb = r & 63, z = r >> 6;
  const ushort* Ah = z ? Ah1 : Ah0;
  const ushort* Al = z ? Al1 : Al0;
  const ushort* Bh = z ? Bh1 : Bh0;
  const ushort* Bl = z ? Bl1 : Bl0;
  ushort* Oh = z ? Oh1 : Oh0;
  ushort* Ol = z ? Ol1 : Ol0;
  const int tid = threadIdx.x, lane = tid & 63, w = tid >> 6;
  const int wr = w >> 1, wc = w & 1;
  const int lr = lane & 15, kg = lane >> 4;
  const int m0 = yb * 128, n0 = xb * 128;
  f32x4 acc[4][4] = {};

  for (int k0 = 0; k0 < 1024; k0 += 32) {
    stage_bf16_32(Ah + (size_t)m0 * 1024 + k0, 1024, Ahs, w, lane);
    stage_bf16_32(Al + (size_t)m0 * 1024 + k0, 1024, Als, w, lane);
    stage_bf16_32(Bh + (size_t)n0 * 1024 + k0, 1024, Bhs, w, lane);
    stage_bf16_32(Bl + (size_t)n0 * 1024 + k0, 1024, Bls, w, lane);
    __syncthreads();
    bf16x8 ah[4], al[4], bh[4], bl[4];
#pragma unroll
    for (int m = 0; m < 4; ++m) {
      ah[m] = *reinterpret_cast<bf16x8*>(&Ahs[(wr * 64 + m * 16 + lr) * 32 + kg * 8]);
      al[m] = *reinterpret_cast<bf16x8*>(&Als[(wr * 64 + m * 16 + lr) * 32 + kg * 8]);
    }
#pragma unroll
    for (int n = 0; n < 4; ++n) {
      bh[n] = *reinterpret_cast<bf16x8*>(&Bhs[(wc * 64 + n * 16 + lr) * 32 + kg * 8]);
      bl[n] = *reinterpret_cast<bf16x8*>(&Bls[(wc * 64 + n * 16 + lr) * 32 + kg * 8]);
    }
#pragma unroll
    for (int m = 0; m < 4; ++m)
#pragma unroll
      for (int n = 0; n < 4; ++n) {
        acc[m][n] = MFMA16(ah[m], bh[n], acc[m][n], 0, 0, 0);
        acc[m][n] = MFMA16(ah[m], bl[n], acc[m][n], 0, 0, 0);
        acc[m][n] = MFMA16(al[m], bh[n], acc[m][n], 0, 0, 0);
      }
    __syncthreads();
  }
#pragma unroll
  for (int m = 0; m < 4; ++m)
#pragma unroll
    for (int n = 0; n < 4; ++n)
#pragma unroll
      for (int reg = 0; reg < 4; ++reg) {
        const int gm = m0 + wr * 64 + m * 16 + kg * 4 + reg;
        const int gn = n0 + wc * 64 + n * 16 + lr;
        ushort h, l;
        splitf(acc[m][n][reg], h, l);
        Oh[(size_t)gm * 1024 + gn] = h;
        Ol[(size_t)gm * 1024 + gn] = l;
      }
}

// ---------------------------------------------------------------------------
// v projection, transposed output: v1t[b][d][j] = sum_k Wv[k][d] v[b,j,k].
// Flat grid 512, swizzle: 8 m-blocks sharing a V-tile co-located per XCD.
//   y(m) = (f>>3)&7 ; x(n) = (f&7)+8*(f>>6)
// ---------------------------------------------------------------------------
__global__ __launch_bounds__(256) void proj_v(const ushort* __restrict__ Wvt,
                                              const float* __restrict__ V,
                                              ushort* __restrict__ v1t) {
  __shared__ ushort Ahs[4096];
  __shared__ float Bs[4096];
  const int f = blockIdx.x;
  const int yb = (f >> 3) & 7;
  const int xb = (f & 7) + ((f >> 6) << 3);
  const int tid = threadIdx.x, lane = tid & 63, w = tid >> 6;
  const int wr = w >> 1, wc = w & 1;
  const int lr = lane & 15, kg = lane >> 4;
  const int m0 = yb * 128;   // d-tile
  const int n0 = xb * 128;   // global j tile
  f32x4 acc[4][4] = {};

  for (int k0 = 0; k0 < 1024; k0 += 32) {
    stage_bf16_32(Wvt + (size_t)m0 * 1024 + k0, 1024, Ahs, w, lane);
    stage_f32_32(V + (size_t)n0 * 1024 + k0, 1024, Bs, w, lane);
    __syncthreads();
    bf16x8 ah[4], bh[4];
#pragma unroll
    for (int m = 0; m < 4; ++m)
      ah[m] = *reinterpret_cast<bf16x8*>(&Ahs[(wr * 64 + m * 16 + lr) * 32 + kg * 8]);
#pragma unroll
    for (int n = 0; n < 4; ++n)
      bh[n] = cvt8(&Bs[(wc * 64 + n * 16 + lr) * 32 + kg * 8]);
#pragma unroll
    for (int m = 0; m < 4; ++m)
#pragma unroll
      for (int n = 0; n < 4; ++n)
        acc[m][n] = MFMA16(ah[m], bh[n], acc[m][n], 0, 0, 0);
    __syncthreads();
  }
#pragma unroll
  for (int m = 0; m < 4; ++m)
#pragma unroll
    for (int n = 0; n < 4; ++n)
#pragma unroll
      for (int reg = 0; reg < 4; ++reg) {
        const int gm = m0 + wr * 64 + m * 16 + kg * 4 + reg;  // d
        const int gn = n0 + wc * 64 + n * 16 + lr;            // global j
        const int b = gn >> 11, jj = gn & 2047;
        v1t[((size_t)b << 21) + (size_t)gm * 2048 + jj] = f2bf(acc[m][n][reg]);
      }
}

// ---------------------------------------------------------------------------
// QK^T, bf16x2 split (3 MFMA), causal triangular grid, SPLIT-K halves.
// Flat grid 1088, chunked XCD swizzle: each XCD gets exactly one (b, K-half)
// slice of 136 tiles (shared q1/k1 panels stay in that L2).
// Packed tile output p = ti*(ti+1)/2+tj at (b*136+p)*16384. No masking.
// ---------------------------------------------------------------------------
__global__ __launch_bounds__(256) void qk2(
    const ushort* __restrict__ q1h, const ushort* __restrict__ q1l,
    const ushort* __restrict__ k1h, const ushort* __restrict__ k1l,
    float* __restrict__ scoresA, float* __restrict__ scoresB) {
  __shared__ ushort Ahs[4096], Als[4096], Bhs[4096], Bls[4096];
  const int f = blockIdx.x;
  const int s = (f & 7) * 136 + (f >> 3);
  const int z = s / 544;
  const int rem = s % 544;
  const int b = rem / 136;
  int p = rem % 136, ti = 0, accp = 0;
  while (accp + ti + 1 <= p) { accp += ti + 1; ++ti; }
  const int tj = p - accp;
  const int tid = threadIdx.x, lane = tid & 63, w = tid >> 6;
  const int wr = w >> 1, wc = w & 1;
  const int lr = lane & 15, kg = lane >> 4;
  const int kh0 = z * 512;  // K half
  const ushort* qh = q1h + ((size_t)b * 2048 + ti * 128) * 1024 + kh0;
  const ushort* ql = q1l + ((size_t)b * 2048 + ti * 128) * 1024 + kh0;
  const ushort* kh = k1h + ((size_t)b * 2048 + tj * 128) * 1024 + kh0;
  const ushort* kl = k1l + ((size_t)b * 2048 + tj * 128) * 1024 + kh0;
  f32x4 acc[4][4] = {};

  for (int k0 = 0; k0 < 512; k0 += 32) {
    stage_bf16_32(qh + k0, 1024, Ahs, w, lane);
    stage_bf16_32(ql + k0, 1024, Als, w, lane);
    stage_bf16_32(kh + k0, 1024, Bhs, w, lane);
    stage_bf16_32(kl + k0, 1024, Bls, w, lane);
    __syncthreads();
    bf16x8 ah[4], al[4], bh[4], bl[4];
#pragma unroll
    for (int m = 0; m < 4; ++m) {
      ah[m] = *reinterpret_cast<bf16x8*>(&Ahs[(wr * 64 + m * 16 + lr) * 32 + kg * 8]);
      al[m] = *reinterpret_cast<bf16x8*>(&Als[(wr * 64 + m * 16 + lr) * 32 + kg * 8]);
    }
#pragma unroll
    for (int n = 0; n < 4; ++n) {
      bh[n] = *reinterpret_cast<bf16x8*>(&Bhs[(wc * 64 + n * 16 + lr) * 32 + kg * 8]);
      bl[n] = *reinterpret_cast<bf16x8*>(&Bls[(wc * 64 + n * 16 + lr) * 32 + kg * 8]);
    }
#pragma unroll
    for (int m = 0; m < 4; ++m)
#pragma unroll
      for (int n = 0; n < 4; ++n) {
        acc[m][n] = MFMA16(ah[m], bh[n], acc[m][n], 0, 0, 0);
        acc[m][n] = MFMA16(ah[m], bl[n], acc[m][n], 0, 0, 0);
        acc[m][n] = MFMA16(al[m], bh[n], acc[m][n], 0, 0, 0);
      }
    __syncthreads();
  }
  const float sc = 0.03125f;  // 1/sqrt(1024)
  float* st = (z ? scoresB : scoresA) + ((size_t)b * 136 + p) * 16384;
#pragma unroll
  for (int m = 0; m < 4; ++m)
#pragma unroll
    for (int n = 0; n < 4; ++n)
#pragma unroll
      for (int reg = 0; reg < 4; ++reg) {
        const int il = wr * 64 + m * 16 + kg * 4 + reg;
        const int jl = wc * 64 + n * 16 + lr;
        st[il * 128 + jl] = acc[m][n][reg] * sc;
      }
}

// ---------------------------------------------------------------------------
// Row softmax over packed tiles, merging split-K partials. Vectorized:
// each thread owns 2 groups of 4 consecutive j (float4 loads, ushort4 P
// stores). P written bf16 in place over scoresA tiles (pitch 256 ushorts).
// ---------------------------------------------------------------------------
__global__ __launch_bounds__(256) void softmax_kernel(
    float* __restrict__ scoresA, const float* __restrict__ scoresB) {
  __shared__ float red[8];
  const int rb = blockIdx.x;
  const int b = rb >> 11, r = rb & 2047;
  const int ti = r >> 7, rl = r & 127, ncol = (ti + 1) * 128;
  const int valid = r + 1;
  const size_t tbase = ((size_t)b * 136 + (ti * (ti + 1)) / 2) * 16384;
  float* srowA = scoresA + tbase;
  const float* srowB = scoresB + tbase;
  const int tid = threadIdx.x, lane = tid & 63, w = tid >> 6;

  float vals[2][4];
  float mx = -FLT_MAX;
#pragma unroll
  for (int c = 0; c < 2; ++c) {
    const int j = tid * 4 + c * 1024;
    const size_t o = (size_t)(j >> 7) * 16384 + rl * 128 + (j & 127);
    const float4 a = *reinterpret_cast<const float4*>(srowA + o);
    const float4 bb = *reinterpret_cast<const float4*>(srowB + o);
    vals[c][0] = (j + 0 < valid) ? a.x + bb.x : -FLT_MAX;
    vals[c][1] = (j + 1 < valid) ? a.y + bb.y : -FLT_MAX;
    vals[c][2] = (j + 2 < valid) ? a.z + bb.z : -FLT_MAX;
    vals[c][3] = (j + 3 < valid) ? a.w + bb.w : -FLT_MAX;
    mx = fmaxf(mx, fmaxf(fmaxf(vals[c][0], vals[c][1]),
                         fmaxf(vals[c][2], vals[c][3])));
  }
#pragma unroll
  for (int o = 32; o; o >>= 1) mx = fmaxf(mx, __shfl_xor(mx, o));
  if (lane == 0) red[w] = mx;
  __syncthreads();
  mx = fmaxf(fmaxf(red[0], red[1]), fmaxf(red[2], red[3]));

  float ex[2][4];
  float sum = 0.f;
#pragma unroll
  for (int c = 0; c < 2; ++c)
#pragma unroll
    for (int e = 0; e < 4; ++e) {
      const int j = tid * 4 + c * 1024 + e;
      ex[c][e] = (j < valid) ? __expf(vals[c][e] - mx) : 0.f;
      sum += ex[c][e];
    }
#pragma unroll
  for (int o = 32; o; o >>= 1) sum += __shfl_xor(sum, o);
  if (lane == 0) red[4 + w] = sum;
  __syncthreads();
  sum = red[4] + red[5] + red[6] + red[7];
  const float inv = 1.f / sum;
#pragma unroll
  for (int c = 0; c < 2; ++c) {
    const int j = tid * 4 + c * 1024;
    if (j < ncol) {
      ushort* pt = reinterpret_cast<ushort*>(srowA + (size_t)(j >> 7) * 16384);
      ushort4 pw;
      pw.x = f2bf(ex[c][0] * inv); pw.y = f2bf(ex[c][1] * inv);
      pw.z = f2bf(ex[c][2] * inv); pw.w = f2bf(ex[c][3] * inv);
      *reinterpret_cast<ushort4*>(&pt[rl * 256 + (j & 127)]) = pw;
    }
  }
}

// ---------------------------------------------------------------------------
// PV: out[b,i,:] = P[b,i,:] @ v1. P bf16 packed tiles (pitch 256 ushorts),
// V from v1t (pitch 2048), BK=64. K ends at (ti+1)*128.
// Flat grid 512, chunked XCD swizzle (same-ti P-panel sharers co-located).
// ---------------------------------------------------------------------------
__global__ __launch_bounds__(256) void pv2(const float* __restrict__ scores,
                                           const ushort* __restrict__ v1t,
                                           float* __restrict__ out) {
  __shared__ ushort Ps[128 * 64], Vs[128 * 64];
  const int fl = blockIdx.x;
  const int s = (fl & 7) * 64 + (fl >> 3);
  const int xb = s & 7, yb = (s >> 3) & 15, b = s >> 7;
  const int tid = threadIdx.x, lane = tid & 63, w = tid >> 6;
  const int wr = w >> 1, wc = w & 1;
  const int lr = lane & 15, kg = lane >> 4;
  const int ti = 15 - yb;  // long blocks first within each chunk
  const int n0 = xb * 128;
  const int tri_ti = (ti * (ti + 1)) / 2;
  const ushort* vbase = v1t + ((size_t)b << 21) + (size_t)n0 * 2048;
  const int kend = (ti + 1) * 128;
  f32x4 acc[4][4] = {};

  for (int k0 = 0; k0 < kend; k0 += 64) {
    const ushort* pt = reinterpret_cast<const ushort*>(
        scores + ((size_t)b * 136 + tri_ti + (k0 >> 7)) * 16384);
    stage_bf16_64(pt + (k0 & 64), 256, Ps, w, lane);
    stage_bf16_64(vbase + k0, 2048, Vs, w, lane);
    __syncthreads();
#pragma unroll
    for (int t2 = 0; t2 < 2; ++t2) {
      bf16x8 pa[4], vb[4];
#pragma unroll
      for (int m = 0; m < 4; ++m)
        pa[m] = *reinterpret_cast<bf16x8*>(
            &Ps[(wr * 64 + m * 16 + lr) * 64 + t2 * 32 + kg * 8]);
#pragma unroll
      for (int n = 0; n < 4; ++n)
        vb[n] = *reinterpret_cast<bf16x8*>(
            &Vs[(wc * 64 + n * 16 + lr) * 64 + t2 * 32 + kg * 8]);
#pragma unroll
      for (int m = 0; m < 4; ++m)
#pragma unroll
        for (int n = 0; n < 4; ++n)
          acc[m][n] = MFMA16(pa[m], vb[n], acc[m][n], 0, 0, 0);
    }
    __syncthreads();
  }
#pragma unroll
  for (int m = 0; m < 4; ++m)
#pragma unroll
    for (int n = 0; n < 4; ++n)
#pragma unroll
      for (int reg = 0; reg < 4; ++reg) {
        const int gm = ti * 128 + wr * 64 + m * 16 + kg * 4 + reg;
        const int gn = n0 + wc * 64 + n * 16 + lr;
        out[((size_t)b * 2048 + gm) * 1024 + gn] = acc[m][n][reg];
      }
}

extern "C" void kernel_launch(void* const* d_in, const int* in_sizes, int n_in,
                              void* d_out, int out_size, void* d_ws,
                              size_t ws_size, hipStream_t stream) {
  const float* q = (const float*)d_in[0];
  const float* k = (const float*)d_in[1];
  const float* v = (const float*)d_in[2];
  // d_in[3] = causal mask — statically known, ignored.
  const float* Wq = (const float*)d_in[4];
  const float* Wk = (const float*)d_in[5];
  const float* Wv = (const float*)d_in[6];
  float* out = (float*)d_out;

  // Workspace (148.9 MB), liveness-aliased:
  //  [0, 71.3M)       qsh,qsl,ksh,ksl (64MB, dead after proj_qk)
  //                   -> scoresA [0,34M), scoresB [34,68M) from qk2 on
  //  [71.3, 138.4M)   q1hi q1lo k1hi k1lo (4x16M, dead after qk2)
  //                   -> v1t [71.3, 88.1M) from proj_v (runs after softmax)
  //  [138.4, 148.9M)  Wq/Wk transposed hi/lo (8M, dead after proj_qk); Wvt
  char* ws = (char*)d_ws;
  const size_t SCORES_T = 35651584;  // 4*136*16384*4
  float* scoresA = (float*)ws;
  float* scoresB = (float*)(ws + SCORES_T);
  ushort* qsh = (ushort*)ws;  // 16 MiB each, alias scores region
  ushort* qsl = qsh + 8388608;
  ushort* ksh = qsh + 2 * 8388608;
  ushort* ksl = qsh + 3 * 8388608;
  ushort* q1hi = (ushort*)(ws + 2 * SCORES_T);  // 16 MiB each
  ushort* q1lo = q1hi + 8388608;
  ushort* k1hi = q1hi + 2 * 8388608;
  ushort* k1lo = q1hi + 3 * 8388608;
  ushort* v1t = (ushort*)(ws + 2 * SCORES_T);  // aliases q1hi/q1lo (dead)
  ushort* Wqth = (ushort*)(ws + 2 * SCORES_T + 67108864);  // 2 MiB each
  ushort* Wqtl = Wqth + 1048576;
  ushort* Wkth = Wqth + 2097152;
  ushort* Wktl = Wqth + 3145728;
  ushort* Wvt  = Wqth + 4194304;
  const size_t need = 2 * SCORES_T + 67108864 + 10485760;  // 148,897,792
  if (ws_size < need) return;

  dim3 blk(256);
  wt_conv<<<dim3(32, 32, 3), blk, 0, stream>>>(Wq, Wk, Wv, Wqth, Wqtl, Wkth,
                                               Wktl, Wvt);
  split_pre<<<dim3(2048, 2), blk, 0, stream>>>(q, k, qsh, qsl, ksh, ksl);
  proj_qk<<<dim3(1024), blk, 0, stream>>>(qsh, qsl, ksh, ksl, Wqth, Wqtl,
                                          Wkth, Wktl, q1hi, q1lo, k1hi, k1lo);
  qk2<<<dim3(1088), blk, 0, stream>>>(q1hi, q1lo, k1hi, k1lo, scoresA,
                                      scoresB);
  softmax_kernel<<<dim3(8192), blk, 0, stream>>>(scoresA, scoresB);
  proj_v<<<dim3(512), blk, 0, stream>>>(Wvt, v, v1t);
  pv2<<<dim3(512), blk, 0, stream>>>(scoresA, v1t, out);
}

// Round 8
// 312.569 us; speedup vs baseline: 1.2748x; 1.0074x over previous
//
#include <hip/hip_runtime.h>
#include <hip/hip_bf16.h>
#include <float.h>

// B=4, S=2048, D=1024 causal attention with input projections.
// out = softmax(mask((q@Wq)(k@Wk)^T / 32)) @ (v@Wv)
//
// Numerics: logits std ~342 -> q/k path uses bf16x2 (hi/lo RTN) split
// arithmetic (3 MFMAs per product), ~2^-18 effective. RTN mandatory
// (truncation split = 4x error, failed R2). v path plain bf16.
//
// R8: launch-graph compaction + occupancy for the small kernels.
//  - wt_conv + split_pre merged into one launch (overlap two BW-bound preps).
//  - proj_v merged into the softmax launch (independent MFMA work overlaps
//    BW-bound softmax; v1t alias of dead q1/k1 still legal).
//  - pv2 retiled 128x128 -> 128x64 (512 -> 1024 blocks, 2 -> 4/CU).
//  proj_qk/qk2 untouched (both at the ~900 TF 2-barrier structure ceiling
//  with near-ideal FETCH after R7's XCD swizzles).

typedef __attribute__((ext_vector_type(8))) short bf16x8;
typedef __attribute__((ext_vector_type(4))) float f32x4;

#define MFMA16 __builtin_amdgcn_mfma_f32_16x16x32_bf16

union U8 { bf16x8 v; unsigned w[4]; };

__device__ __forceinline__ ushort f2bf(float x) {
  union { float f; unsigned u; } v; v.f = x;
  unsigned r = v.u + 0x7fffu + ((v.u >> 16) & 1u);
  return (ushort)(r >> 16);
}
__device__ __forceinline__ float bf2f(ushort h) {
  union { unsigned u; float f; } v; v.u = ((unsigned)h) << 16;
  return v.f;
}
__device__ __forceinline__ void splitf(float x, ushort& hi, ushort& lo) {
  hi = f2bf(x);
  lo = f2bf(x - bf2f(hi));
}

// Plain fp32 -> bf16x8 (RTN) from 8 consecutive LDS floats (proj_v only).
__device__ __forceinline__ bf16x8 cvt8(const float* lp) {
  U8 H;
#pragma unroll
  for (int p = 0; p < 4; ++p) {
    const unsigned u0 = __float_as_uint(lp[2 * p]);
    const unsigned u1 = __float_as_uint(lp[2 * p + 1]);
    const unsigned r0 = (u0 + 0x7fffu + ((u0 >> 16) & 1u)) >> 16;
    const unsigned r1 = (u1 + 0x7fffu + ((u1 >> 16) & 1u)) & 0xffff0000u;
    H.w[p] = r0 | r1;
  }
  return H.v;
}

// ---------------------------------------------------------------------------
// global_load_lds staging. LDS linear (no pad). Chunk = 1024 B.
// ---------------------------------------------------------------------------
#define GLOAD16(gp, lp)                                                        \
  __builtin_amdgcn_global_load_lds(                                            \
      (const __attribute__((address_space(1))) void*)(gp),                     \
      (__attribute__((address_space(3))) void*)(lp), 16, 0, 0)

// bf16 slab 128 x 32 (8 KB, 8 chunks)
__device__ __forceinline__ void stage_bf16_32(const ushort* g, int pitch,
                                              ushort* lds, int w, int lane) {
#pragma unroll
  for (int i = 0; i < 2; ++i) {
    const int c = w * 2 + i;
    const int row = c * 16 + (lane >> 2);
    const int kp = (lane & 3) * 8;
    GLOAD16(g + (size_t)row * pitch + kp, lds + c * 512);
  }
}
// bf16 slab 128 x 64 (16 KB, 16 chunks)
__device__ __forceinline__ void stage_bf16_64(const ushort* g, int pitch,
                                              ushort* lds, int w, int lane) {
#pragma unroll
  for (int i = 0; i < 4; ++i) {
    const int c = w * 4 + i;
    const int row = c * 8 + (lane >> 3);
    const int kp = (lane & 7) * 8;
    GLOAD16(g + (size_t)row * pitch + kp, lds + c * 512);
  }
}
// bf16 slab 64 x 64 (8 KB, 8 chunks)
__device__ __forceinline__ void stage_bf16_64x64(const ushort* g, int pitch,
                                                 ushort* lds, int w, int lane) {
#pragma unroll
  for (int i = 0; i < 2; ++i) {
    const int c = w * 2 + i;
    const int row = c * 8 + (lane >> 3);
    const int kp = (lane & 7) * 8;
    GLOAD16(g + (size_t)row * pitch + kp, lds + c * 512);
  }
}
// fp32 slab 128 x 32 (16 KB, 16 chunks)
__device__ __forceinline__ void stage_f32_32(const float* g, int pitch,
                                             float* lds, int w, int lane) {
#pragma unroll
  for (int i = 0; i < 4; ++i) {
    const int c = w * 4 + i;
    const int row = c * 8 + (lane >> 3);
    const int kp = (lane & 7) * 4;
    GLOAD16(g + (size_t)row * pitch + kp, lds + c * 256);
  }
}

// ---------------------------------------------------------------------------
// Merged prepass: f < 3072 -> W transpose+convert (z = f>>10);
//                 f >= 3072 -> q/k fp32 -> hi/lo bf16 split (grid-stride).
// ---------------------------------------------------------------------------
__global__ __launch_bounds__(256) void wt_split(
    const float* __restrict__ q, const float* __restrict__ k,
    const float* __restrict__ W0, const float* __restrict__ W1,
    const float* __restrict__ W2, ushort* __restrict__ Th0,
    ushort* __restrict__ Tl0, ushort* __restrict__ Th1,
    ushort* __restrict__ Tl1, ushort* __restrict__ Th2,
    ushort* __restrict__ qh, ushort* __restrict__ ql,
    ushort* __restrict__ kh, ushort* __restrict__ kl) {
  __shared__ float t[32][33];
  const int f = blockIdx.x;
  if (f < 3072) {
    const int z = f >> 10, r10 = f & 1023;
    const int bx = r10 & 31, by = r10 >> 5;  // k-tile, n-tile
    const float* W = z == 0 ? W0 : (z == 1 ? W1 : W2);
    ushort* Th = z == 0 ? Th0 : (z == 1 ? Th1 : Th2);
    ushort* Tl = z == 0 ? Tl0 : (z == 1 ? Tl1 : nullptr);
    const int r = threadIdx.x >> 3, c4 = (threadIdx.x & 7) * 4;
    const float4 x = *reinterpret_cast<const float4*>(
        &W[(size_t)(bx * 32 + r) * 1024 + by * 32 + c4]);
    t[r][c4] = x.x; t[r][c4 + 1] = x.y; t[r][c4 + 2] = x.z; t[r][c4 + 3] = x.w;
    __syncthreads();
    ushort h[4], l[4];
#pragma unroll
    for (int j = 0; j < 4; ++j) splitf(t[c4 + j][r], h[j], l[j]);
    const size_t o = (size_t)(by * 32 + r) * 1024 + bx * 32 + c4;
    *reinterpret_cast<ushort4*>(&Th[o]) = ushort4{h[0], h[1], h[2], h[3]};
    if (Tl)
      *reinterpret_cast<ushort4*>(&Tl[o]) = ushort4{l[0], l[1], l[2], l[3]};
  } else {
    const int fl = f - 3072;
    const float* X = (fl >> 11) ? k : q;
    ushort* H = (fl >> 11) ? kh : qh;
    ushort* L = (fl >> 11) ? kl : ql;
    const int n4 = 2097152;  // 8192*1024/4
    for (int i = (fl & 2047) * 256 + threadIdx.x; i < n4; i += 2048 * 256) {
      const float4 x = reinterpret_cast<const float4*>(X)[i];
      ushort h0, l0, h1, l1, h2, l2, h3, l3;
      splitf(x.x, h0, l0); splitf(x.y, h1, l1);
      splitf(x.z, h2, l2); splitf(x.w, h3, l3);
      reinterpret_cast<ushort4*>(H)[i] = ushort4{h0, h1, h2, h3};
      reinterpret_cast<ushort4*>(L)[i] = ushort4{l0, l1, l2, l3};
    }
  }
}

// ---------------------------------------------------------------------------
// q/k projection, pre-split operands both sides, 3 MFMA per tile pair.
// Flat grid 1024, XCD swizzle: 8 n-blocks sharing one A-slab -> same XCD.
// ---------------------------------------------------------------------------
__global__ __launch_bounds__(256) void proj_qk(
    const ushort* __restrict__ Ah0, const ushort* __restrict__ Al0,
    const ushort* __restrict__ Ah1, const ushort* __restrict__ Al1,
    const ushort* __restrict__ Bh0, const ushort* __restrict__ Bl0,
    const ushort* __restrict__ Bh1, const ushort* __restrict__ Bl1,
    ushort* __restrict__ Oh0, ushort* __restrict__ Ol0,
    ushort* __restrict__ Oh1, ushort* __restrict__ Ol1) {
  __shared__ ushort Ahs[4096], Als[4096], Bhs[4096], Bls[4096];
  const int f = blockIdx.x;
  const int xb = (f >> 3) & 7;
  const int r = (f & 7) + ((f >> 6) << 3);
  const int yb = r & 63, z = r >> 6;
  const ushort* Ah = z ? Ah1 : Ah0;
  const ushort* Al = z ? Al1 : Al0;
  const ushort* Bh = z ? Bh1 : Bh0;
  const ushort* Bl = z ? Bl1 : Bl0;
  ushort* Oh = z ? Oh1 : Oh0;
  ushort* Ol = z ? Ol1 : Ol0;
  const int tid = threadIdx.x, lane = tid & 63, w = tid >> 6;
  const int wr = w >> 1, wc = w & 1;
  const int lr = lane & 15, kg = lane >> 4;
  const int m0 = yb * 128, n0 = xb * 128;
  f32x4 acc[4][4] = {};

  for (int k0 = 0; k0 < 1024; k0 += 32) {
    stage_bf16_32(Ah + (size_t)m0 * 1024 + k0, 1024, Ahs, w, lane);
    stage_bf16_32(Al + (size_t)m0 * 1024 + k0, 1024, Als, w, lane);
    stage_bf16_32(Bh + (size_t)n0 * 1024 + k0, 1024, Bhs, w, lane);
    stage_bf16_32(Bl + (size_t)n0 * 1024 + k0, 1024, Bls, w, lane);
    __syncthreads();
    bf16x8 ah[4], al[4], bh[4], bl[4];
#pragma unroll
    for (int m = 0; m < 4; ++m) {
      ah[m] = *reinterpret_cast<bf16x8*>(&Ahs[(wr * 64 + m * 16 + lr) * 32 + kg * 8]);
      al[m] = *reinterpret_cast<bf16x8*>(&Als[(wr * 64 + m * 16 + lr) * 32 + kg * 8]);
    }
#pragma unroll
    for (int n = 0; n < 4; ++n) {
      bh[n] = *reinterpret_cast<bf16x8*>(&Bhs[(wc * 64 + n * 16 + lr) * 32 + kg * 8]);
      bl[n] = *reinterpret_cast<bf16x8*>(&Bls[(wc * 64 + n * 16 + lr) * 32 + kg * 8]);
    }
#pragma unroll
    for (int m = 0; m < 4; ++m)
#pragma unroll
      for (int n = 0; n < 4; ++n) {
        acc[m][n] = MFMA16(ah[m], bh[n], acc[m][n], 0, 0, 0);
        acc[m][n] = MFMA16(ah[m], bl[n], acc[m][n], 0, 0, 0);
        acc[m][n] = MFMA16(al[m], bh[n], acc[m][n], 0, 0, 0);
      }
    __syncthreads();
  }
#pragma unroll
  for (int m = 0; m < 4; ++m)
#pragma unroll
    for (int n = 0; n < 4; ++n)
#pragma unroll
      for (int reg = 0; reg < 4; ++reg) {
        const int gm = m0 + wr * 64 + m * 16 + kg * 4 + reg;
        const int gn = n0 + wc * 64 + n * 16 + lr;
        ushort h, l;
        splitf(acc[m][n][reg], h, l);
        Oh[(size_t)gm * 1024 + gn] = h;
        Ol[(size_t)gm * 1024 + gn] = l;
      }
}

// ---------------------------------------------------------------------------
// QK^T, bf16x2 split (3 MFMA), causal triangular grid, SPLIT-K halves.
// Flat grid 1088, chunked XCD swizzle. Packed tile output. No masking.
// ---------------------------------------------------------------------------
__global__ __launch_bounds__(256) void qk2(
    const ushort* __restrict__ q1h, const ushort* __restrict__ q1l,
    const ushort* __restrict__ k1h, const ushort* __restrict__ k1l,
    float* __restrict__ scoresA, float* __restrict__ scoresB) {
  __shared__ ushort Ahs[4096], Als[4096], Bhs[4096], Bls[4096];
  const int f = blockIdx.x;
  const int s = (f & 7) * 136 + (f >> 3);
  const int z = s / 544;
  const int rem = s % 544;
  const int b = rem / 136;
  int p = rem % 136, ti = 0, accp = 0;
  while (accp + ti + 1 <= p) { accp += ti + 1; ++ti; }
  const int tj = p - accp;
  const int tid = threadIdx.x, lane = tid & 63, w = tid >> 6;
  const int wr = w >> 1, wc = w & 1;
  const int lr = lane & 15, kg = lane >> 4;
  const int kh0 = z * 512;  // K half
  const ushort* qh = q1h + ((size_t)b * 2048 + ti * 128) * 1024 + kh0;
  const ushort* ql = q1l + ((size_t)b * 2048 + ti * 128) * 1024 + kh0;
  const ushort* kh = k1h + ((size_t)b * 2048 + tj * 128) * 1024 + kh0;
  const ushort* kl = k1l + ((size_t)b * 2048 + tj * 128) * 1024 + kh0;
  f32x4 acc[4][4] = {};

  for (int k0 = 0; k0 < 512; k0 += 32) {
    stage_bf16_32(qh + k0, 1024, Ahs, w, lane);
    stage_bf16_32(ql + k0, 1024, Als, w, lane);
    stage_bf16_32(kh + k0, 1024, Bhs, w, lane);
    stage_bf16_32(kl + k0, 1024, Bls, w, lane);
    __syncthreads();
    bf16x8 ah[4], al[4], bh[4], bl[4];
#pragma unroll
    for (int m = 0; m < 4; ++m) {
      ah[m] = *reinterpret_cast<bf16x8*>(&Ahs[(wr * 64 + m * 16 + lr) * 32 + kg * 8]);
      al[m] = *reinterpret_cast<bf16x8*>(&Als[(wr * 64 + m * 16 + lr) * 32 + kg * 8]);
    }
#pragma unroll
    for (int n = 0; n < 4; ++n) {
      bh[n] = *reinterpret_cast<bf16x8*>(&Bhs[(wc * 64 + n * 16 + lr) * 32 + kg * 8]);
      bl[n] = *reinterpret_cast<bf16x8*>(&Bls[(wc * 64 + n * 16 + lr) * 32 + kg * 8]);
    }
#pragma unroll
    for (int m = 0; m < 4; ++m)
#pragma unroll
      for (int n = 0; n < 4; ++n) {
        acc[m][n] = MFMA16(ah[m], bh[n], acc[m][n], 0, 0, 0);
        acc[m][n] = MFMA16(ah[m], bl[n], acc[m][n], 0, 0, 0);
        acc[m][n] = MFMA16(al[m], bh[n], acc[m][n], 0, 0, 0);
      }
    __syncthreads();
  }
  const float sc = 0.03125f;  // 1/sqrt(1024)
  float* st = (z ? scoresB : scoresA) + ((size_t)b * 136 + p) * 16384;
#pragma unroll
  for (int m = 0; m < 4; ++m)
#pragma unroll
    for (int n = 0; n < 4; ++n)
#pragma unroll
      for (int reg = 0; reg < 4; ++reg) {
        const int il = wr * 64 + m * 16 + kg * 4 + reg;
        const int jl = wc * 64 + n * 16 + lr;
        st[il * 128 + jl] = acc[m][n][reg] * sc;
      }
}

// ---------------------------------------------------------------------------
// Merged: f < 8192 -> row softmax (split-K partial merge, vectorized, P bf16
// in place over scoresA tiles). f >= 8192 -> proj_v (v1t[b][d][j], overlaps
// softmax's BW-bound phase with MFMA work; v1t aliases dead q1/k1).
// ---------------------------------------------------------------------------
__global__ __launch_bounds__(256) void sm_projv(
    float* __restrict__ scoresA, const float* __restrict__ scoresB,
    const ushort* __restrict__ Wvt, const float* __restrict__ V,
    ushort* __restrict__ v1t) {
  __shared__ __align__(16) char smem[24576];
  const int tid = threadIdx.x, lane = tid & 63, w = tid >> 6;
  const int fg = blockIdx.x;
  if (fg < 8192) {
    float* red = reinterpret_cast<float*>(smem);
    const int b = fg >> 11, r = fg & 2047;
    const int ti = r >> 7, rl = r & 127, ncol = (ti + 1) * 128;
    const int valid = r + 1;
    const size_t tbase = ((size_t)b * 136 + (ti * (ti + 1)) / 2) * 16384;
    float* srowA = scoresA + tbase;
    const float* srowB = scoresB + tbase;

    float vals[2][4];
    float mx = -FLT_MAX;
#pragma unroll
    for (int c = 0; c < 2; ++c) {
      const int j = tid * 4 + c * 1024;
      const size_t o = (size_t)(j >> 7) * 16384 + rl * 128 + (j & 127);
      const float4 a = *reinterpret_cast<const float4*>(srowA + o);
      const float4 bb = *reinterpret_cast<const float4*>(srowB + o);
      vals[c][0] = (j + 0 < valid) ? a.x + bb.x : -FLT_MAX;
      vals[c][1] = (j + 1 < valid) ? a.y + bb.y : -FLT_MAX;
      vals[c][2] = (j + 2 < valid) ? a.z + bb.z : -FLT_MAX;
      vals[c][3] = (j + 3 < valid) ? a.w + bb.w : -FLT_MAX;
      mx = fmaxf(mx, fmaxf(fmaxf(vals[c][0], vals[c][1]),
                           fmaxf(vals[c][2], vals[c][3])));
    }
#pragma unroll
    for (int o = 32; o; o >>= 1) mx = fmaxf(mx, __shfl_xor(mx, o));
    if (lane == 0) red[w] = mx;
    __syncthreads();
    mx = fmaxf(fmaxf(red[0], red[1]), fmaxf(red[2], red[3]));

    float ex[2][4];
    float sum = 0.f;
#pragma unroll
    for (int c = 0; c < 2; ++c)
#pragma unroll
      for (int e = 0; e < 4; ++e) {
        const int j = tid * 4 + c * 1024 + e;
        ex[c][e] = (j < valid) ? __expf(vals[c][e] - mx) : 0.f;
        sum += ex[c][e];
      }
#pragma unroll
    for (int o = 32; o; o >>= 1) sum += __shfl_xor(sum, o);
    if (lane == 0) red[4 + w] = sum;
    __syncthreads();
    sum = red[4] + red[5] + red[6] + red[7];
    const float inv = 1.f / sum;
#pragma unroll
    for (int c = 0; c < 2; ++c) {
      const int j = tid * 4 + c * 1024;
      if (j < ncol) {
        ushort* pt =
            reinterpret_cast<ushort*>(srowA + (size_t)(j >> 7) * 16384);
        ushort4 pw;
        pw.x = f2bf(ex[c][0] * inv); pw.y = f2bf(ex[c][1] * inv);
        pw.z = f2bf(ex[c][2] * inv); pw.w = f2bf(ex[c][3] * inv);
        *reinterpret_cast<ushort4*>(&pt[rl * 256 + (j & 127)]) = pw;
      }
    }
  } else {
    // proj_v: v1t[b][d][j] = sum_k Wv[k][d] v[b,j,k]
    ushort* Ahs = reinterpret_cast<ushort*>(smem);            // 8 KB
    float* Bs = reinterpret_cast<float*>(smem + 8192);        // 16 KB
    const int f2 = fg - 8192;
    const int yb = (f2 >> 3) & 7;
    const int xb = (f2 & 7) + ((f2 >> 6) << 3);
    const int wr = w >> 1, wc = w & 1;
    const int lr = lane & 15, kg = lane >> 4;
    const int m0 = yb * 128;   // d-tile
    const int n0 = xb * 128;   // global j tile
    f32x4 acc[4][4] = {};

    for (int k0 = 0; k0 < 1024; k0 += 32) {
      stage_bf16_32(Wvt + (size_t)m0 * 1024 + k0, 1024, Ahs, w, lane);
      stage_f32_32(V + (size_t)n0 * 1024 + k0, 1024, Bs, w, lane);
      __syncthreads();
      bf16x8 ah[4], bh[4];
#pragma unroll
      for (int m = 0; m < 4; ++m)
        ah[m] = *reinterpret_cast<bf16x8*>(
            &Ahs[(wr * 64 + m * 16 + lr) * 32 + kg * 8]);
#pragma unroll
      for (int n = 0; n < 4; ++n)
        bh[n] = cvt8(&Bs[(wc * 64 + n * 16 + lr) * 32 + kg * 8]);
#pragma unroll
      for (int m = 0; m < 4; ++m)
#pragma unroll
        for (int n = 0; n < 4; ++n)
          acc[m][n] = MFMA16(ah[m], bh[n], acc[m][n], 0, 0, 0);
      __syncthreads();
    }
#pragma unroll
    for (int m = 0; m < 4; ++m)
#pragma unroll
      for (int n = 0; n < 4; ++n)
#pragma unroll
        for (int reg = 0; reg < 4; ++reg) {
          const int gm = m0 + wr * 64 + m * 16 + kg * 4 + reg;  // d
          const int gn = n0 + wc * 64 + n * 16 + lr;            // global j
          const int b = gn >> 11, jj = gn & 2047;
          v1t[((size_t)b << 21) + (size_t)gm * 2048 + jj] = f2bf(acc[m][n][reg]);
        }
  }
}

// ---------------------------------------------------------------------------
// PV: out[b,i,:] = P[b,i,:] @ v1. Retiled 128x64 (1024 blocks, 4/CU, 24 KB
// LDS). P bf16 packed tiles (pitch 256 ushorts), V from v1t (pitch 2048),
// BK=64, K ends at (ti+1)*128. Chunked XCD swizzle.
// ---------------------------------------------------------------------------
__global__ __launch_bounds__(256) void pv2(const float* __restrict__ scores,
                                           const ushort* __restrict__ v1t,
                                           float* __restrict__ out) {
  __shared__ ushort Ps[128 * 64], Vs[64 * 64];
  const int fl = blockIdx.x;  // 1024
  const int s = (fl & 7) * 128 + (fl >> 3);
  const int b = s >> 8, rem = s & 255;
  const int ti = 15 - (rem >> 4);  // long blocks first within each chunk
  const int n0 = (rem & 15) * 64;
  const int tid = threadIdx.x, lane = tid & 63, w = tid >> 6;
  const int wr = w >> 1, wc = w & 1;
  const int lr = lane & 15, kg = lane >> 4;
  const int tri_ti = (ti * (ti + 1)) / 2;
  const ushort* vbase = v1t + ((size_t)b << 21) + (size_t)n0 * 2048;
  const int kend = (ti + 1) * 128;
  f32x4 acc[4][2] = {};

  for (int k0 = 0; k0 < kend; k0 += 64) {
    const ushort* pt = reinterpret_cast<const ushort*>(
        scores + ((size_t)b * 136 + tri_ti + (k0 >> 7)) * 16384);
    stage_bf16_64(pt + (k0 & 64), 256, Ps, w, lane);
    stage_bf16_64x64(vbase + k0, 2048, Vs, w, lane);
    __syncthreads();
#pragma unroll
    for (int t2 = 0; t2 < 2; ++t2) {
      bf16x8 pa[4], vb[2];
#pragma unroll
      for (int m = 0; m < 4; ++m)
        pa[m] = *reinterpret_cast<bf16x8*>(
            &Ps[(wr * 64 + m * 16 + lr) * 64 + t2 * 32 + kg * 8]);
#pragma unroll
      for (int n = 0; n < 2; ++n)
        vb[n] = *reinterpret_cast<bf16x8*>(
            &Vs[(wc * 32 + n * 16 + lr) * 64 + t2 * 32 + kg * 8]);
#pragma unroll
      for (int m = 0; m < 4; ++m)
#pragma unroll
        for (int n = 0; n < 2; ++n)
          acc[m][n] = MFMA16(pa[m], vb[n], acc[m][n], 0, 0, 0);
    }
    __syncthreads();
  }
#pragma unroll
  for (int m = 0; m < 4; ++m)
#pragma unroll
    for (int n = 0; n < 2; ++n)
#pragma unroll
      for (int reg = 0; reg < 4; ++reg) {
        const int gm = ti * 128 + wr * 64 + m * 16 + kg * 4 + reg;
        const int gn = n0 + wc * 32 + n * 16 + lr;
        out[((size_t)b * 2048 + gm) * 1024 + gn] = acc[m][n][reg];
      }
}

extern "C" void kernel_launch(void* const* d_in, const int* in_sizes, int n_in,
                              void* d_out, int out_size, void* d_ws,
                              size_t ws_size, hipStream_t stream) {
  const float* q = (const float*)d_in[0];
  const float* k = (const float*)d_in[1];
  const float* v = (const float*)d_in[2];
  // d_in[3] = causal mask — statically known, ignored.
  const float* Wq = (const float*)d_in[4];
  const float* Wk = (const float*)d_in[5];
  const float* Wv = (const float*)d_in[6];
  float* out = (float*)d_out;

  // Workspace (148.9 MB), liveness-aliased:
  //  [0, 71.3M)       qsh,qsl,ksh,ksl (64MB, dead after proj_qk)
  //                   -> scoresA [0,34M), scoresB [34,68M) from qk2 on
  //  [71.3, 138.4M)   q1hi q1lo k1hi k1lo (4x16M, dead after qk2)
  //                   -> v1t [71.3, 88.1M) from sm_projv on
  //  [138.4, 148.9M)  Wq/Wk transposed hi/lo (8M, dead after proj_qk); Wvt
  char* ws = (char*)d_ws;
  const size_t SCORES_T = 35651584;  // 4*136*16384*4
  float* scoresA = (float*)ws;
  float* scoresB = (float*)(ws + SCORES_T);
  ushort* qsh = (ushort*)ws;  // 16 MiB each, alias scores region
  ushort* qsl = qsh + 8388608;
  ushort* ksh = qsh + 2 * 8388608;
  ushort* ksl = qsh + 3 * 8388608;
  ushort* q1hi = (ushort*)(ws + 2 * SCORES_T);  // 16 MiB each
  ushort* q1lo = q1hi + 8388608;
  ushort* k1hi = q1hi + 2 * 8388608;
  ushort* k1lo = q1hi + 3 * 8388608;
  ushort* v1t = (ushort*)(ws + 2 * SCORES_T);  // aliases q1hi/q1lo (dead)
  ushort* Wqth = (ushort*)(ws + 2 * SCORES_T + 67108864);  // 2 MiB each
  ushort* Wqtl = Wqth + 1048576;
  ushort* Wkth = Wqth + 2097152;
  ushort* Wktl = Wqth + 3145728;
  ushort* Wvt  = Wqth + 4194304;
  const size_t need = 2 * SCORES_T + 67108864 + 10485760;  // 148,897,792
  if (ws_size < need) return;

  dim3 blk(256);
  wt_split<<<dim3(7168), blk, 0, stream>>>(q, k, Wq, Wk, Wv, Wqth, Wqtl, Wkth,
                                           Wktl, Wvt, qsh, qsl, ksh, ksl);
  proj_qk<<<dim3(1024), blk, 0, stream>>>(qsh, qsl, ksh, ksl, Wqth, Wqtl,
                                          Wkth, Wktl, q1hi, q1lo, k1hi, k1lo);
  qk2<<<dim3(1088), blk, 0, stream>>>(q1hi, q1lo, k1hi, k1lo, scoresA,
                                      scoresB);
  sm_projv<<<dim3(8704), blk, 0, stream>>>(scoresA, scoresB, Wvt, v, v1t);
  pv2<<<dim3(1024), blk, 0, stream>>>(scoresA, v1t, out);
}